// Round 13
// baseline (193.791 us; speedup 1.0000x reference)
//
#include <hip/hip_runtime.h>
#include <math.h>

// Problem constants: B=2, T=2048, C=1024, H=16, Dh=64
#define GB 2
#define GT_SEQ 2048
#define GC 1024
#define GH 16
#define GDH 64
#define GM (GB * GT_SEQ)      // 4096 rows

typedef __attribute__((ext_vector_type(8))) short bf16x8;   // 8 bf16 = 4 VGPRs
typedef __attribute__((ext_vector_type(8))) unsigned short u16x8;
typedef __attribute__((ext_vector_type(4))) unsigned short u16x4;
typedef __attribute__((ext_vector_type(4))) float f32x4;
typedef unsigned int u32;

#define QSCALE 0.18033688f   // 0.125 * log2(e): QK^T lands in log2 domain

__device__ __forceinline__ unsigned short f2bf(float f) {   // RNE f32 -> bf16
    unsigned int u = __float_as_uint(f);
    u += 0x7FFFu + ((u >> 16) & 1u);
    return (unsigned short)(u >> 16);
}
__device__ __forceinline__ float bf2f(unsigned short u) {   // exact bf16 -> f32
    return __uint_as_float(((unsigned int)u) << 16);
}
__device__ __forceinline__ float hw_exp2(float x) {         // v_exp_f32
    return __builtin_amdgcn_exp2f(x);
}
// pack 2 f32 -> u32 of 2 bf16 (lo in low half); validated rounds 9-10
__device__ __forceinline__ u32 pack2bf(float lo, float hi) {
    return ((u32)f2bf(hi) << 16) | (u32)f2bf(lo);
}

// async global->LDS, 16B per lane; LDS dest is wave-uniform base (+lane*16 by HW)
#define GLOAD_LDS16(g, l) __builtin_amdgcn_global_load_lds( \
    (const __attribute__((address_space(1))) void*)(g),      \
    (__attribute__((address_space(3))) void*)(l), 16, 0, 0)

// swizzled fragment read: rows of 64 bf16 (128B = 8 chunks), chunk ^= (row&7)
__device__ __forceinline__ bf16x8 frag_ld(const char* base, int r, int kch) {
    return *reinterpret_cast<const bf16x8*>(base + r * 128 + ((kch ^ (r & 7)) << 4));
}

// ---------------- fused cast f32 -> bf16 (x | w_attn | w_proj, one launch) ----------------
__global__ __launch_bounds__(256) void cast3_f32_bf16(
    const float* __restrict__ a, unsigned short* __restrict__ oa, int na,
    const float* __restrict__ b, unsigned short* __restrict__ ob, int nb,
    const float* __restrict__ c, unsigned short* __restrict__ oc)
{
    const int i = (blockIdx.x * 256 + threadIdx.x) * 4;
    const float* src; unsigned short* dst; int off;
    if (i < na)            { src = a; dst = oa; off = i; }
    else if (i < na + nb)  { src = b; dst = ob; off = i - na; }
    else                   { src = c; dst = oc; off = i - na - nb; }
    const float4 v = *reinterpret_cast<const float4*>(&src[off]);
    ushort4 o;
    o.x = f2bf(v.x); o.y = f2bf(v.y); o.z = f2bf(v.z); o.w = f2bf(v.w);
    *reinterpret_cast<ushort4*>(&dst[off]) = o;
}

// ---------------- bf16 MFMA GEMM: C = A @ B^T + bias (validated rounds 2-11) ----------------
__global__ __launch_bounds__(256) void gemm_mfma_bt(
    const unsigned short* __restrict__ A,   // [M][K] bf16
    const unsigned short* __restrict__ B,   // [N][K] bf16
    const float* __restrict__ bias,         // [N] f32
    float* __restrict__ Cf,                 // f32 out
    int M, int N, int K)
{
    __shared__ char As[128 * 128];
    __shared__ char Bs[128 * 128];

    const int tid  = threadIdx.x;
    const int lane = tid & 63;
    const int w    = tid >> 6;
    const int wm   = w >> 1;
    const int wn   = w & 1;
    const int m0 = blockIdx.y * 128;
    const int n0 = blockIdx.x * 128;

    f32x4 acc[4][4];
#pragma unroll
    for (int i = 0; i < 4; ++i)
#pragma unroll
        for (int j = 0; j < 4; ++j) acc[i][j] = (f32x4){0.f, 0.f, 0.f, 0.f};

    const int wbase = (tid & ~63);

    for (int k0 = 0; k0 < K; k0 += 64) {
        const char* Ag = (const char*)(A + (size_t)m0 * K + k0);
        const char* Bg = (const char*)(B + (size_t)n0 * K + k0);
#pragma unroll
        for (int i = 0; i < 4; ++i) {
            const int c = i * 256 + tid;
            const int row = c >> 3, cin = c & 7;
            const size_t goff = (size_t)row * (K * 2) + (size_t)((cin ^ (row & 7)) << 4);
            GLOAD_LDS16(Ag + goff, As + (i * 256 + wbase) * 16);
            GLOAD_LDS16(Bg + goff, Bs + (i * 256 + wbase) * 16);
        }
        __syncthreads();

#pragma unroll
        for (int ks = 0; ks < 2; ++ks) {
            const int kch = ks * 4 + (lane >> 4);
            bf16x8 a[4], b[4];
#pragma unroll
            for (int mi = 0; mi < 4; ++mi)
                a[mi] = frag_ld(As, wm * 64 + mi * 16 + (lane & 15), kch);
#pragma unroll
            for (int ni = 0; ni < 4; ++ni)
                b[ni] = frag_ld(Bs, wn * 64 + ni * 16 + (lane & 15), kch);
#pragma unroll
            for (int mi = 0; mi < 4; ++mi)
#pragma unroll
                for (int ni = 0; ni < 4; ++ni)
                    acc[mi][ni] = __builtin_amdgcn_mfma_f32_16x16x32_bf16(
                        a[mi], b[ni], acc[mi][ni], 0, 0, 0);
        }
        __syncthreads();
    }

    const int lc  = lane & 15;
    const int lr4 = (lane >> 4) * 4;
#pragma unroll
    for (int ni = 0; ni < 4; ++ni) {
        const int gcol = n0 + wn * 64 + ni * 16 + lc;
        const float bv = bias[gcol];
#pragma unroll
        for (int mi = 0; mi < 4; ++mi) {
            const int grow0 = m0 + wm * 64 + mi * 16 + lr4;
#pragma unroll
            for (int j = 0; j < 4; ++j)
                Cf[(size_t)(grow0 + j) * N + gcol] = acc[mi][ni][j] + bv;
        }
    }
}

// ---------------- GEMM1 fused: qkv projection -> per-head Qh (scaled), Kh, Vh ----------------
__global__ __launch_bounds__(256) void gemm_qkv(
    const unsigned short* __restrict__ A,    // [4096][1024] bf16 (x)
    const unsigned short* __restrict__ B,    // [3072][1024] bf16 (w_attn)
    const float* __restrict__ bias,          // [3072]
    unsigned short* __restrict__ Qh,         // [32][2048][64]
    unsigned short* __restrict__ Kh,
    unsigned short* __restrict__ Vh)
{
    __shared__ char As[128 * 128];
    __shared__ char Bs[128 * 128];

    const int N = 3 * GC, K = GC;
    const int tid  = threadIdx.x;
    const int lane = tid & 63;
    const int w    = tid >> 6;
    const int wm   = w >> 1;
    const int wn   = w & 1;
    const int m0 = blockIdx.y * 128;
    const int n0 = blockIdx.x * 128;

    f32x4 acc[4][4];
#pragma unroll
    for (int i = 0; i < 4; ++i)
#pragma unroll
        for (int j = 0; j < 4; ++j) acc[i][j] = (f32x4){0.f, 0.f, 0.f, 0.f};

    const int wbase = (tid & ~63);

    for (int k0 = 0; k0 < K; k0 += 64) {
        const char* Ag = (const char*)(A + (size_t)m0 * K + k0);
        const char* Bg = (const char*)(B + (size_t)n0 * K + k0);
#pragma unroll
        for (int i = 0; i < 4; ++i) {
            const int c = i * 256 + tid;
            const int row = c >> 3, cin = c & 7;
            const size_t goff = (size_t)row * (K * 2) + (size_t)((cin ^ (row & 7)) << 4);
            GLOAD_LDS16(Ag + goff, As + (i * 256 + wbase) * 16);
            GLOAD_LDS16(Bg + goff, Bs + (i * 256 + wbase) * 16);
        }
        __syncthreads();

#pragma unroll
        for (int ks = 0; ks < 2; ++ks) {
            const int kch = ks * 4 + (lane >> 4);
            bf16x8 a[4], b[4];
#pragma unroll
            for (int mi = 0; mi < 4; ++mi)
                a[mi] = frag_ld(As, wm * 64 + mi * 16 + (lane & 15), kch);
#pragma unroll
            for (int ni = 0; ni < 4; ++ni)
                b[ni] = frag_ld(Bs, wn * 64 + ni * 16 + (lane & 15), kch);
#pragma unroll
            for (int mi = 0; mi < 4; ++mi)
#pragma unroll
                for (int ni = 0; ni < 4; ++ni)
                    acc[mi][ni] = __builtin_amdgcn_mfma_f32_16x16x32_bf16(
                        a[mi], b[ni], acc[mi][ni], 0, 0, 0);
        }
        __syncthreads();
    }

    const int lc  = lane & 15;
    const int lr4 = (lane >> 4) * 4;
#pragma unroll
    for (int ni = 0; ni < 4; ++ni) {
        const int gcol = n0 + wn * 64 + ni * 16 + lc;   // 0..3071
        const float bv  = bias[gcol];
        const int sel = gcol >> 10;                      // 0=q 1=k 2=v
        const int h   = (gcol >> 6) & 15;
        const int d   = gcol & 63;
        unsigned short* dst = (sel == 0) ? Qh : ((sel == 1) ? Kh : Vh);
        const float scl = (sel == 0) ? QSCALE : 1.f;
#pragma unroll
        for (int mi = 0; mi < 4; ++mi) {
            const int grow0 = m0 + wm * 64 + mi * 16 + lr4;
#pragma unroll
            for (int j = 0; j < 4; ++j) {
                const int grow = grow0 + j;
                const int bb = grow >> 11, t = grow & (GT_SEQ - 1);
                dst[((size_t)(bb * GH + h) * GT_SEQ + t) * GDH + d] =
                    f2bf((acc[mi][ni][j] + bv) * scl);
            }
        }
    }
}

// ---------------- V transpose: Vh[bh][t][d] -> Vt[bh][d][t] ----------------
__global__ __launch_bounds__(256) void transpose_v(
    const unsigned short* __restrict__ Vh, unsigned short* __restrict__ Vt)
{
    __shared__ unsigned short vt[64][72];
    const int tid = threadIdx.x;
    const int t0  = blockIdx.x * 64;
    const int bh  = blockIdx.y;
    const unsigned short* src = Vh + (size_t)bh * GT_SEQ * GDH;
    unsigned short* dstb = Vt + (size_t)bh * GDH * GT_SEQ;

#pragma unroll
    for (int i = 0; i < 2; ++i) {
        const int c = i * 256 + tid;
        const int tr = c >> 3, ch = c & 7;
        *reinterpret_cast<u16x8*>(&vt[tr][ch * 8]) =
            *reinterpret_cast<const u16x8*>(src + (size_t)(t0 + tr) * GDH + ch * 8);
    }
    __syncthreads();
#pragma unroll
    for (int i = 0; i < 2; ++i) {
        const int c = i * 256 + tid;
        const int d = c >> 3, ch = c & 7;
        u16x8 o;
#pragma unroll
        for (int e = 0; e < 8; ++e) o[e] = vt[ch * 8 + e][d];
        *reinterpret_cast<u16x8*>(dstb + (size_t)d * GT_SEQ + t0 + ch * 8) = o;
    }
}

// ---------------- flash attention v7b: dual-unit waves (b=0 and b=1 paired) ----------------
// Block = 128 threads (2 waves), one (h, qt) PAIR: unit u = batch u, same qt ->
// identical control flow, two independent dep chains per wave (2x ILP). Wave wv
// does key tiles kt ≡ wv (mod 2); end merge via LDS (per unit, sequential).
// v5c core: swapped mfma(K,Q), in-lane softmax, in-register P via pack2bf,
// slot perm k = 32s+16(e>>2)+4*l4+(e&3) on BOTH P and V^T (validated r9-r10).
// Row sums: in-lane f32 partials (linear -> *=corr valid), shfl-reduced at end.
// r12 bug: grid arithmetic gave 512 blocks (half the (h,qt) pairs) -> fixed: 1024.
__global__ __launch_bounds__(128) void flash_attn_mfma7(
    const unsigned short* __restrict__ Qh,   // [32][2048][64], pre-scaled
    const unsigned short* __restrict__ Kh,   // [32][2048][64]
    const unsigned short* __restrict__ Vt,   // [32][64][2048]
    unsigned short* __restrict__ O)          // [4096][1024] bf16
{
    __shared__ float Of[32][68];             // deposit buffer (reused per unit)
    __shared__ float ml_lds[2][2][2][32];    // [unit][wave][m|l][row]

    const int tid  = threadIdx.x;
    const int lane = tid & 63;
    const int wv   = tid >> 6;               // 0 or 1
    const int l15  = lane & 15;
    const int l4   = lane >> 4;
    const int bid  = blockIdx.x;              // 0..1023
    // XCD swizzle: xcd (bid&7) serves 2 heads (both batches); heavy q-tiles first
    const int xcd = bid & 7;
    const int idx = bid >> 3;                 // 0..127
    const int h   = xcd * 2 + (idx & 1);      // 0..15
    const int qt  = 63 - (idx >> 1);          // 0..63, heavy first
    const int q0w = qt * 32;

    const unsigned short* hQ[2];
    const unsigned short* hK[2];
    const unsigned short* hV[2];
#pragma unroll
    for (int u = 0; u < 2; ++u) {
        const int bh = u * GH + h;
        hQ[u] = Qh + (size_t)bh * GT_SEQ * GDH;
        hK[u] = Kh + (size_t)bh * GT_SEQ * GDH;
        hV[u] = Vt + (size_t)bh * GDH * GT_SEQ;
    }

    // Q fragments (pre-scaled, B-operand): qf[u][mi][s], q = mi*16+l15, d = s*32+l4*8+e
    bf16x8 qf[2][2][2];
#pragma unroll
    for (int u = 0; u < 2; ++u)
#pragma unroll
        for (int mi = 0; mi < 2; ++mi)
#pragma unroll
            for (int s = 0; s < 2; ++s)
                qf[u][mi][s] = *reinterpret_cast<const bf16x8*>(
                    hQ[u] + (size_t)(q0w + mi * 16 + l15) * GDH + s * 32 + l4 * 8);

    // accumulators: acc_o[u][mi][nd]: O[q=mi*16+l15][d = nd*16 + l4*4 + j]
    f32x4 acc_o[2][2][4];
    float l_part[2][2];        // in-lane partial row sum (this lane's 16 k-slots)
    float m_r[2][2];           // running max, row-consistent
#pragma unroll
    for (int u = 0; u < 2; ++u)
#pragma unroll
        for (int mi = 0; mi < 2; ++mi) {
            l_part[u][mi] = 0.f;
            m_r[u][mi] = -1e30f;
#pragma unroll
            for (int nd = 0; nd < 4; ++nd)
                acc_o[u][mi][nd] = (f32x4){0.f, 0.f, 0.f, 0.f};
        }

    const int nt = qt / 2 + 1;

    for (int kt = wv; kt < nt; kt += 2) {
        const int k0 = kt * 64;

        // ---- QK^T swapped, both units: S^T = mfma(K, Q) ----
        // s_acc[u][mi][ni]: S[q=mi*16+l15][k = k0 + ni*16 + l4*4 + j]
        f32x4 s_acc[2][2][4];
#pragma unroll
        for (int u = 0; u < 2; ++u)
#pragma unroll
            for (int mi = 0; mi < 2; ++mi)
#pragma unroll
                for (int ni = 0; ni < 4; ++ni)
                    s_acc[u][mi][ni] = (f32x4){0.f, 0.f, 0.f, 0.f};
#pragma unroll
        for (int s = 0; s < 2; ++s) {
            bf16x8 kf[2][4];
#pragma unroll
            for (int u = 0; u < 2; ++u)
#pragma unroll
                for (int ni = 0; ni < 4; ++ni)
                    kf[u][ni] = *reinterpret_cast<const bf16x8*>(
                        hK[u] + (size_t)(k0 + ni * 16 + l15) * GDH + s * 32 + l4 * 8);
#pragma unroll
            for (int u = 0; u < 2; ++u)
#pragma unroll
                for (int ni = 0; ni < 4; ++ni)
#pragma unroll
                    for (int mi = 0; mi < 2; ++mi)
                        s_acc[u][mi][ni] = __builtin_amdgcn_mfma_f32_16x16x32_bf16(
                            kf[u][ni], qf[u][mi][s], s_acc[u][mi][ni], 0, 0, 0);
        }

        // ---- causal mask (partial tiles only): k > q -> -inf ----
        if (k0 + 63 > q0w) {
#pragma unroll
            for (int u = 0; u < 2; ++u)
#pragma unroll
                for (int mi = 0; mi < 2; ++mi)
#pragma unroll
                    for (int ni = 0; ni < 4; ++ni)
#pragma unroll
                        for (int j = 0; j < 4; ++j)
                            if (k0 + ni * 16 + l4 * 4 + j > q0w + mi * 16 + l15)
                                s_acc[u][mi][ni][j] = -1e30f;
        }

        // ---- deferred-max: in-lane partial max, combined wave check ----
        float rp[2][2];
        int ok = 1;
#pragma unroll
        for (int u = 0; u < 2; ++u)
#pragma unroll
            for (int mi = 0; mi < 2; ++mi) {
                float r = fmaxf(fmaxf(s_acc[u][mi][0][0], s_acc[u][mi][0][1]),
                                fmaxf(s_acc[u][mi][0][2], s_acc[u][mi][0][3]));
#pragma unroll
                for (int ni = 1; ni < 4; ++ni)
                    r = fmaxf(r, fmaxf(fmaxf(s_acc[u][mi][ni][0], s_acc[u][mi][ni][1]),
                                       fmaxf(s_acc[u][mi][ni][2], s_acc[u][mi][ni][3])));
                rp[u][mi] = r;
                ok &= (r <= m_r[u][mi] + 8.f) ? 1 : 0;
            }
        if (!__all(ok)) {   // rare slow path: full row max + rescale (both units)
#pragma unroll
            for (int u = 0; u < 2; ++u)
#pragma unroll
                for (int mi = 0; mi < 2; ++mi) {
                    float r = rp[u][mi];
                    r = fmaxf(r, __shfl_xor(r, 16));
                    r = fmaxf(r, __shfl_xor(r, 32));
                    const float mnew = fmaxf(m_r[u][mi], r);
                    const float corr = hw_exp2(m_r[u][mi] - mnew);
                    m_r[u][mi] = mnew;
                    l_part[u][mi] *= corr;
#pragma unroll
                    for (int nd = 0; nd < 4; ++nd) acc_o[u][mi][nd] *= corr;
                }
        }

        // ---- exp2 + pack + PV per s, both units (P never leaves registers) ----
#pragma unroll
        for (int s = 0; s < 2; ++s) {
            u16x4 vb[2][4][2];
#pragma unroll
            for (int u = 0; u < 2; ++u)
#pragma unroll
                for (int nd = 0; nd < 4; ++nd) {
                    const unsigned short* vr = hV[u] + (size_t)(nd * 16 + l15) * GT_SEQ
                                             + k0 + s * 32 + l4 * 4;
                    vb[u][nd][0] = *reinterpret_cast<const u16x4*>(vr);
                    vb[u][nd][1] = *reinterpret_cast<const u16x4*>(vr + 16);
                }
            union { u32 w[4]; bf16x8 v; } pw[2][2];
#pragma unroll
            for (int u = 0; u < 2; ++u)
#pragma unroll
                for (int mi = 0; mi < 2; ++mi) {
                    f32x4 pa, pb;
#pragma unroll
                    for (int j = 0; j < 4; ++j) {
                        pa[j] = hw_exp2(s_acc[u][mi][2 * s + 0][j] - m_r[u][mi]);
                        pb[j] = hw_exp2(s_acc[u][mi][2 * s + 1][j] - m_r[u][mi]);
                    }
                    l_part[u][mi] += (pa[0] + pa[1]) + (pa[2] + pa[3])
                                   + (pb[0] + pb[1]) + (pb[2] + pb[3]);
                    pw[u][mi].w[0] = pack2bf(pa[0], pa[1]);
                    pw[u][mi].w[1] = pack2bf(pa[2], pa[3]);
                    pw[u][mi].w[2] = pack2bf(pb[0], pb[1]);
                    pw[u][mi].w[3] = pack2bf(pb[2], pb[3]);
                }
#pragma unroll
            for (int u = 0; u < 2; ++u)
#pragma unroll
                for (int nd = 0; nd < 4; ++nd) {
                    union { u16x4 h2[2]; bf16x8 v; } vbs;
                    vbs.h2[0] = vb[u][nd][0];
                    vbs.h2[1] = vb[u][nd][1];
#pragma unroll
                    for (int mi = 0; mi < 2; ++mi)
                        acc_o[u][mi][nd] = __builtin_amdgcn_mfma_f32_16x16x32_bf16(
                            vbs.v, pw[u][mi].v, acc_o[u][mi][nd], 0, 0, 0);
                }
        }
    }

    // ---- finalize row sums: reduce in-lane partials over the 4 l4 lanes ----
    float lfull[2][2];
#pragma unroll
    for (int u = 0; u < 2; ++u)
#pragma unroll
        for (int mi = 0; mi < 2; ++mi) {
            float lp = l_part[u][mi];
            lp += __shfl_xor(lp, 16);
            lp += __shfl_xor(lp, 32);
            lfull[u][mi] = lp;
        }

    // ---- publish per-unit (m, l) ----
    if (l4 == 0) {
#pragma unroll
        for (int u = 0; u < 2; ++u)
#pragma unroll
            for (int mi = 0; mi < 2; ++mi) {
                ml_lds[u][wv][0][mi * 16 + l15] = m_r[u][mi];
                ml_lds[u][wv][1][mi * 16 + l15] = lfull[u][mi];
            }
    }
    __syncthreads();

    // ---- merge per unit (sequential through shared Of buffer) ----
#pragma unroll
    for (int u = 0; u < 2; ++u) {
        if (wv == 0) {   // wave0 deposits rescaled O
#pragma unroll
            for (int mi = 0; mi < 2; ++mi) {
                const int row = mi * 16 + l15;
                const float m1 = ml_lds[u][1][0][row];
                const float mm = fmaxf(m_r[u][mi], m1);
                const float s0 = hw_exp2(m_r[u][mi] - mm);
#pragma unroll
                for (int nd = 0; nd < 4; ++nd) {
                    f32x4 o = acc_o[u][mi][nd] * s0;
                    *reinterpret_cast<f32x4*>(&Of[row][nd * 16 + l4 * 4]) = o;
                }
            }
        }
        __syncthreads();
        if (wv == 1) {   // wave1 combines and stores
#pragma unroll
            for (int mi = 0; mi < 2; ++mi) {
                const int row = mi * 16 + l15;
                const float m0v = ml_lds[u][0][0][row];
                const float l0v = ml_lds[u][0][1][row];
                const float l1v = lfull[u][mi];
                const float mm  = fmaxf(m0v, m_r[u][mi]);
                const float s0  = hw_exp2(m0v - mm);
                const float s1  = hw_exp2(m_r[u][mi] - mm);
                const float inv = 1.f / (l0v * s0 + l1v * s1);
                const size_t rbase = (size_t)(u * GT_SEQ + q0w + row) * GC + h * GDH;
#pragma unroll
                for (int nd = 0; nd < 4; ++nd) {
                    const f32x4 o0 = *reinterpret_cast<const f32x4*>(&Of[row][nd * 16 + l4 * 4]);
                    ushort4 ov;
                    ov.x = f2bf((o0[0] + acc_o[u][mi][nd][0] * s1) * inv);
                    ov.y = f2bf((o0[1] + acc_o[u][mi][nd][1] * s1) * inv);
                    ov.z = f2bf((o0[2] + acc_o[u][mi][nd][2] * s1) * inv);
                    ov.w = f2bf((o0[3] + acc_o[u][mi][nd][3] * s1) * inv);
                    *reinterpret_cast<ushort4*>(&O[rbase + nd * 16 + l4 * 4]) = ov;
                }
            }
        }
        __syncthreads();
    }
}

extern "C" void kernel_launch(void* const* d_in, const int* in_sizes, int n_in,
                              void* d_out, int out_size, void* d_ws, size_t ws_size,
                              hipStream_t stream) {
    (void)in_sizes; (void)n_in; (void)out_size; (void)ws_size;
    const float* x      = (const float*)d_in[0];
    const float* w_attn = (const float*)d_in[1];
    const float* b_attn = (const float*)d_in[2];
    const float* w_proj = (const float*)d_in[3];
    const float* b_proj = (const float*)d_in[4];
    float* out = (float*)d_out;

    unsigned short* xb  = (unsigned short*)d_ws;             // [4096][1024]
    unsigned short* wab = xb  + (size_t)GM * GC;             // [3072][1024]
    unsigned short* wpb = wab + (size_t)3 * GC * GC;         // [1024][1024]
    unsigned short* Qh  = wpb + (size_t)GC * GC;             // [32][2048][64]
    unsigned short* Kh  = Qh  + (size_t)4 * 1024 * 1024;
    unsigned short* Vh  = Kh  + (size_t)4 * 1024 * 1024;
    unsigned short* Vt  = Vh  + (size_t)4 * 1024 * 1024;     // [32][64][2048]
    unsigned short* aob = xb;   // reuse: xb dead after GEMM1

    // 0) fused casts (one launch): x(4M) | w_attn(3M) | w_proj(1M) = 8M elems
    cast3_f32_bf16<<<dim3(8192), dim3(256), 0, stream>>>(
        x, xb, GM * GC, w_attn, wab, 3 * GC * GC, w_proj, wpb);

    // 1) fused qkv projection -> Qh (scaled), Kh, Vh
    gemm_qkv<<<dim3(3 * GC / 128, GM / 128), dim3(256), 0, stream>>>(
        xb, wab, b_attn, Qh, Kh, Vh);

    // 1.5) V transpose -> Vt
    transpose_v<<<dim3(GT_SEQ / 64, GB * GH), dim3(256), 0, stream>>>(Vh, Vt);

    // 2) flash attention v7b (dual-unit waves) -> aob [B,T,C] bf16
    //    grid = H * (T/32) = 16 * 64 = 1024 blocks, one (h,qt) pair each (both batches)
    flash_attn_mfma7<<<dim3(GH * (GT_SEQ / 32)), dim3(128), 0, stream>>>(
        Qh, Kh, Vt, aob);

    // 3) out = aob @ w_proj^T + b_proj (f32)
    gemm_mfma_bt<<<dim3(GC / 128, GM / 128), dim3(256), 0, stream>>>(
        aob, wpb, b_proj, out, GM, GC, GC);
}

// Round 14
// 137.206 us; speedup vs baseline: 1.4124x; 1.4124x over previous
//
#include <hip/hip_runtime.h>
#include <math.h>

// Problem constants: B=2, T=2048, C=1024, H=16, Dh=64
#define GB 2
#define GT_SEQ 2048
#define GC 1024
#define GH 16
#define GDH 64
#define GM (GB * GT_SEQ)      // 4096 rows

typedef __attribute__((ext_vector_type(8))) short bf16x8;   // 8 bf16 = 4 VGPRs
typedef __attribute__((ext_vector_type(8))) unsigned short u16x8;
typedef __attribute__((ext_vector_type(4))) unsigned short u16x4;
typedef __attribute__((ext_vector_type(4))) float f32x4;
typedef unsigned int u32;

#define QSCALE 0.18033688f   // 0.125 * log2(e): QK^T lands in log2 domain

__device__ __forceinline__ unsigned short f2bf(float f) {   // RNE f32 -> bf16
    unsigned int u = __float_as_uint(f);
    u += 0x7FFFu + ((u >> 16) & 1u);
    return (unsigned short)(u >> 16);
}
__device__ __forceinline__ float bf2f(unsigned short u) {   // exact bf16 -> f32
    return __uint_as_float(((unsigned int)u) << 16);
}
__device__ __forceinline__ float hw_exp2(float x) {         // v_exp_f32
    return __builtin_amdgcn_exp2f(x);
}
// pack 2 f32 -> u32 of 2 bf16 (lo in low half); validated rounds 9-13
__device__ __forceinline__ u32 pack2bf(float lo, float hi) {
    return ((u32)f2bf(hi) << 16) | (u32)f2bf(lo);
}

// async global->LDS, 16B per lane; LDS dest is wave-uniform base (+lane*16 by HW)
#define GLOAD_LDS16(g, l) __builtin_amdgcn_global_load_lds( \
    (const __attribute__((address_space(1))) void*)(g),      \
    (__attribute__((address_space(3))) void*)(l), 16, 0, 0)

// swizzled fragment read: rows of 64 bf16 (128B = 8 chunks), chunk ^= (row&7)
__device__ __forceinline__ bf16x8 frag_ld(const char* base, int r, int kch) {
    return *reinterpret_cast<const bf16x8*>(base + r * 128 + ((kch ^ (r & 7)) << 4));
}

// ---------------- fused cast f32 -> bf16 (x | w_attn | w_proj, one launch) ----------------
__global__ __launch_bounds__(256) void cast3_f32_bf16(
    const float* __restrict__ a, unsigned short* __restrict__ oa, int na,
    const float* __restrict__ b, unsigned short* __restrict__ ob, int nb,
    const float* __restrict__ c, unsigned short* __restrict__ oc)
{
    const int i = (blockIdx.x * 256 + threadIdx.x) * 4;
    const float* src; unsigned short* dst; int off;
    if (i < na)            { src = a; dst = oa; off = i; }
    else if (i < na + nb)  { src = b; dst = ob; off = i - na; }
    else                   { src = c; dst = oc; off = i - na - nb; }
    const float4 v = *reinterpret_cast<const float4*>(&src[off]);
    ushort4 o;
    o.x = f2bf(v.x); o.y = f2bf(v.y); o.z = f2bf(v.z); o.w = f2bf(v.w);
    *reinterpret_cast<ushort4*>(&dst[off]) = o;
}

// ---------------- bf16 MFMA GEMM: C = A @ B^T + bias (validated rounds 2-13) ----------------
__global__ __launch_bounds__(256) void gemm_mfma_bt(
    const unsigned short* __restrict__ A,   // [M][K] bf16
    const unsigned short* __restrict__ B,   // [N][K] bf16
    const float* __restrict__ bias,         // [N] f32
    float* __restrict__ Cf,                 // f32 out
    int M, int N, int K)
{
    __shared__ char As[128 * 128];
    __shared__ char Bs[128 * 128];

    const int tid  = threadIdx.x;
    const int lane = tid & 63;
    const int w    = tid >> 6;
    const int wm   = w >> 1;
    const int wn   = w & 1;
    const int m0 = blockIdx.y * 128;
    const int n0 = blockIdx.x * 128;

    f32x4 acc[4][4];
#pragma unroll
    for (int i = 0; i < 4; ++i)
#pragma unroll
        for (int j = 0; j < 4; ++j) acc[i][j] = (f32x4){0.f, 0.f, 0.f, 0.f};

    const int wbase = (tid & ~63);

    for (int k0 = 0; k0 < K; k0 += 64) {
        const char* Ag = (const char*)(A + (size_t)m0 * K + k0);
        const char* Bg = (const char*)(B + (size_t)n0 * K + k0);
#pragma unroll
        for (int i = 0; i < 4; ++i) {
            const int c = i * 256 + tid;
            const int row = c >> 3, cin = c & 7;
            const size_t goff = (size_t)row * (K * 2) + (size_t)((cin ^ (row & 7)) << 4);
            GLOAD_LDS16(Ag + goff, As + (i * 256 + wbase) * 16);
            GLOAD_LDS16(Bg + goff, Bs + (i * 256 + wbase) * 16);
        }
        __syncthreads();

#pragma unroll
        for (int ks = 0; ks < 2; ++ks) {
            const int kch = ks * 4 + (lane >> 4);
            bf16x8 a[4], b[4];
#pragma unroll
            for (int mi = 0; mi < 4; ++mi)
                a[mi] = frag_ld(As, wm * 64 + mi * 16 + (lane & 15), kch);
#pragma unroll
            for (int ni = 0; ni < 4; ++ni)
                b[ni] = frag_ld(Bs, wn * 64 + ni * 16 + (lane & 15), kch);
#pragma unroll
            for (int mi = 0; mi < 4; ++mi)
#pragma unroll
                for (int ni = 0; ni < 4; ++ni)
                    acc[mi][ni] = __builtin_amdgcn_mfma_f32_16x16x32_bf16(
                        a[mi], b[ni], acc[mi][ni], 0, 0, 0);
        }
        __syncthreads();
    }

    const int lc  = lane & 15;
    const int lr4 = (lane >> 4) * 4;
#pragma unroll
    for (int ni = 0; ni < 4; ++ni) {
        const int gcol = n0 + wn * 64 + ni * 16 + lc;
        const float bv = bias[gcol];
#pragma unroll
        for (int mi = 0; mi < 4; ++mi) {
            const int grow0 = m0 + wm * 64 + mi * 16 + lr4;
#pragma unroll
            for (int j = 0; j < 4; ++j)
                Cf[(size_t)(grow0 + j) * N + gcol] = acc[mi][ni][j] + bv;
        }
    }
}

// ---------------- GEMM1 fused: qkv projection -> per-head Qh (scaled), Kh, Vh ----------------
__global__ __launch_bounds__(256) void gemm_qkv(
    const unsigned short* __restrict__ A,    // [4096][1024] bf16 (x)
    const unsigned short* __restrict__ B,    // [3072][1024] bf16 (w_attn)
    const float* __restrict__ bias,          // [3072]
    unsigned short* __restrict__ Qh,         // [32][2048][64]
    unsigned short* __restrict__ Kh,
    unsigned short* __restrict__ Vh)
{
    __shared__ char As[128 * 128];
    __shared__ char Bs[128 * 128];

    const int N = 3 * GC, K = GC;
    const int tid  = threadIdx.x;
    const int lane = tid & 63;
    const int w    = tid >> 6;
    const int wm   = w >> 1;
    const int wn   = w & 1;
    const int m0 = blockIdx.y * 128;
    const int n0 = blockIdx.x * 128;

    f32x4 acc[4][4];
#pragma unroll
    for (int i = 0; i < 4; ++i)
#pragma unroll
        for (int j = 0; j < 4; ++j) acc[i][j] = (f32x4){0.f, 0.f, 0.f, 0.f};

    const int wbase = (tid & ~63);

    for (int k0 = 0; k0 < K; k0 += 64) {
        const char* Ag = (const char*)(A + (size_t)m0 * K + k0);
        const char* Bg = (const char*)(B + (size_t)n0 * K + k0);
#pragma unroll
        for (int i = 0; i < 4; ++i) {
            const int c = i * 256 + tid;
            const int row = c >> 3, cin = c & 7;
            const size_t goff = (size_t)row * (K * 2) + (size_t)((cin ^ (row & 7)) << 4);
            GLOAD_LDS16(Ag + goff, As + (i * 256 + wbase) * 16);
            GLOAD_LDS16(Bg + goff, Bs + (i * 256 + wbase) * 16);
        }
        __syncthreads();

#pragma unroll
        for (int ks = 0; ks < 2; ++ks) {
            const int kch = ks * 4 + (lane >> 4);
            bf16x8 a[4], b[4];
#pragma unroll
            for (int mi = 0; mi < 4; ++mi)
                a[mi] = frag_ld(As, wm * 64 + mi * 16 + (lane & 15), kch);
#pragma unroll
            for (int ni = 0; ni < 4; ++ni)
                b[ni] = frag_ld(Bs, wn * 64 + ni * 16 + (lane & 15), kch);
#pragma unroll
            for (int mi = 0; mi < 4; ++mi)
#pragma unroll
                for (int ni = 0; ni < 4; ++ni)
                    acc[mi][ni] = __builtin_amdgcn_mfma_f32_16x16x32_bf16(
                        a[mi], b[ni], acc[mi][ni], 0, 0, 0);
        }
        __syncthreads();
    }

    const int lc  = lane & 15;
    const int lr4 = (lane >> 4) * 4;
#pragma unroll
    for (int ni = 0; ni < 4; ++ni) {
        const int gcol = n0 + wn * 64 + ni * 16 + lc;   // 0..3071
        const float bv  = bias[gcol];
        const int sel = gcol >> 10;                      // 0=q 1=k 2=v
        const int h   = (gcol >> 6) & 15;
        const int d   = gcol & 63;
        unsigned short* dst = (sel == 0) ? Qh : ((sel == 1) ? Kh : Vh);
        const float scl = (sel == 0) ? QSCALE : 1.f;
#pragma unroll
        for (int mi = 0; mi < 4; ++mi) {
            const int grow0 = m0 + wm * 64 + mi * 16 + lr4;
#pragma unroll
            for (int j = 0; j < 4; ++j) {
                const int grow = grow0 + j;
                const int bb = grow >> 11, t = grow & (GT_SEQ - 1);
                dst[((size_t)(bb * GH + h) * GT_SEQ + t) * GDH + d] =
                    f2bf((acc[mi][ni][j] + bv) * scl);
            }
        }
    }
}

// ---------------- V transpose: Vh[bh][t][d] -> Vt[bh][d][t] ----------------
__global__ __launch_bounds__(256) void transpose_v(
    const unsigned short* __restrict__ Vh, unsigned short* __restrict__ Vt)
{
    __shared__ unsigned short vt[64][72];
    const int tid = threadIdx.x;
    const int t0  = blockIdx.x * 64;
    const int bh  = blockIdx.y;
    const unsigned short* src = Vh + (size_t)bh * GT_SEQ * GDH;
    unsigned short* dstb = Vt + (size_t)bh * GDH * GT_SEQ;

#pragma unroll
    for (int i = 0; i < 2; ++i) {
        const int c = i * 256 + tid;
        const int tr = c >> 3, ch = c & 7;
        *reinterpret_cast<u16x8*>(&vt[tr][ch * 8]) =
            *reinterpret_cast<const u16x8*>(src + (size_t)(t0 + tr) * GDH + ch * 8);
    }
    __syncthreads();
#pragma unroll
    for (int i = 0; i < 2; ++i) {
        const int c = i * 256 + tid;
        const int d = c >> 3, ch = c & 7;
        u16x8 o;
#pragma unroll
        for (int e = 0; e < 8; ++e) o[e] = vt[ch * 8 + e][d];
        *reinterpret_cast<u16x8*>(dstb + (size_t)d * GT_SEQ + t0 + ch * 8) = o;
    }
}

// ---------------- flash attention v8: 4-wave block, LDS-shared K/V double-buffer ----------------
// Block = 256 threads (4 waves), one (bh, 128-row q-block); wave w owns rows
// w*32..+31 completely (no merge, no K-split). Per 64-key tile, K (8KB) and V^T
// (8KB) staged ONCE into LDS via global_load_lds (pre-swizzled source, linear
// dest — rule 21), double-buffered, one barrier per tile. 4x less L2 traffic
// than per-wave register loads (the r6-r13 wall). Per-wave compute core is the
// validated v7b single-unit: swapped mfma(K,Q), in-lane softmax + deferred max,
// in-register P via pack2bf, slot perm k = 32s+16(e>>2)+4*l4+(e&3) on P and V^T.
__global__ __launch_bounds__(256) void flash_attn_mfma8(
    const unsigned short* __restrict__ Qh,   // [32][2048][64], pre-scaled
    const unsigned short* __restrict__ Kh,   // [32][2048][64]
    const unsigned short* __restrict__ Vt,   // [32][64][2048]
    unsigned short* __restrict__ O)          // [4096][1024] bf16
{
    __shared__ __align__(16) char Ks[2][64 * 128];   // K tile: row k (0..63), 64 d bf16, swizzled
    __shared__ __align__(16) char Vs[2][64 * 128];   // V^T tile: row d (0..63), 64 t bf16, swizzled

    const int tid  = threadIdx.x;
    const int lane = tid & 63;
    const int w    = tid >> 6;               // wave 0..3
    const int l15  = lane & 15;
    const int l4   = lane >> 4;
    const int bid  = blockIdx.x;              // 0..511
    // XCD swizzle: xcd (bid&7) serves 4 heads-of-32 bh; heavy q-blocks first
    const int xcd  = bid & 7;
    const int rest = bid >> 3;                // 0..63
    const int bh   = xcd * 4 + (rest & 3);    // 0..31
    const int qb   = 15 - (rest >> 2);        // 0..15, heavy first
    const int b    = bh >> 4, h = bh & 15;
    const int q0w  = qb * 128 + w * 32;

    const unsigned short* hQ = Qh + (size_t)bh * GT_SEQ * GDH;
    const char* hKc = (const char*)(Kh + (size_t)bh * GT_SEQ * GDH);
    const char* hVc = (const char*)(Vt + (size_t)bh * GDH * GT_SEQ);

    // Q fragments (pre-scaled, B-operand): qf[mi][s], q = mi*16+l15, d = s*32+l4*8+e
    bf16x8 qf[2][2];
#pragma unroll
    for (int mi = 0; mi < 2; ++mi)
#pragma unroll
        for (int s = 0; s < 2; ++s)
            qf[mi][s] = *reinterpret_cast<const bf16x8*>(
                hQ + (size_t)(q0w + mi * 16 + l15) * GDH + s * 32 + l4 * 8);

    // accumulators: acc_o[mi][nd]: O[q=mi*16+l15][d = nd*16 + l4*4 + j]
    f32x4 acc_o[2][4];
    float l_part[2];           // in-lane partial row sum (this lane's 16 k-slots)
    float m_r[2];              // running max, row-consistent
#pragma unroll
    for (int mi = 0; mi < 2; ++mi) {
        l_part[mi] = 0.f;
        m_r[mi] = -1e30f;
#pragma unroll
        for (int nd = 0; nd < 4; ++nd) acc_o[mi][nd] = (f32x4){0.f, 0.f, 0.f, 0.f};
    }

    const int nt = qb * 2 + 2;               // k-tiles covering q rows [qb*128, qb*128+128)
    const int wbase16 = (tid & ~63) * 16;    // wave-uniform LDS byte base component

    // stage tile t into buffer bb: source pre-swizzled, dest linear (rule 21)
    auto STAGE = [&](int bb, int t) {
        const int k0 = t * 64;
#pragma unroll
        for (int i = 0; i < 2; ++i) {
            const int c = i * 256 + tid;     // linear 16B chunk 0..511
            const int row = c >> 3, cin = c & 7;
            GLOAD_LDS16(hKc + (size_t)(k0 + row) * 128 + ((cin ^ (row & 7)) << 4),
                        Ks[bb] + i * 4096 + wbase16);
            GLOAD_LDS16(hVc + (size_t)row * 4096 + (size_t)k0 * 2 + ((cin ^ (row & 7)) << 4),
                        Vs[bb] + i * 4096 + wbase16);
        }
    };

    STAGE(0, 0);
    __syncthreads();   // drains vmcnt(0): buf0 ready

    for (int t = 0; t < nt; ++t) {
        if (t + 1 < nt) STAGE((t + 1) & 1, t + 1);   // prefetch next tile

        const int k0 = t * 64;
        const char* Kb = Ks[t & 1];
        const char* Vb = Vs[t & 1];

        if (k0 <= q0w + 31) {   // wave-uniform: skip fully-masked tiles (still barrier below)
            // ---- QK^T swapped: S^T = mfma(K, Q), K fragments from LDS ----
            f32x4 s_acc[2][4];
#pragma unroll
            for (int mi = 0; mi < 2; ++mi)
#pragma unroll
                for (int ni = 0; ni < 4; ++ni) s_acc[mi][ni] = (f32x4){0.f, 0.f, 0.f, 0.f};
#pragma unroll
            for (int s = 0; s < 2; ++s) {
                bf16x8 kf[4];
#pragma unroll
                for (int ni = 0; ni < 4; ++ni)
                    kf[ni] = frag_ld(Kb, ni * 16 + l15, s * 4 + l4);
#pragma unroll
                for (int ni = 0; ni < 4; ++ni)
#pragma unroll
                    for (int mi = 0; mi < 2; ++mi)
                        s_acc[mi][ni] = __builtin_amdgcn_mfma_f32_16x16x32_bf16(
                            kf[ni], qf[mi][s], s_acc[mi][ni], 0, 0, 0);
            }

            // ---- causal mask (partial tiles only): k > q -> -inf ----
            if (k0 + 63 > q0w) {
#pragma unroll
                for (int mi = 0; mi < 2; ++mi)
#pragma unroll
                    for (int ni = 0; ni < 4; ++ni)
#pragma unroll
                        for (int j = 0; j < 4; ++j)
                            if (k0 + ni * 16 + l4 * 4 + j > q0w + mi * 16 + l15)
                                s_acc[mi][ni][j] = -1e30f;
            }

            // ---- deferred-max: in-lane partial max, rare rescale ----
            float rp[2];
            int ok = 1;
#pragma unroll
            for (int mi = 0; mi < 2; ++mi) {
                float r = fmaxf(fmaxf(s_acc[mi][0][0], s_acc[mi][0][1]),
                                fmaxf(s_acc[mi][0][2], s_acc[mi][0][3]));
#pragma unroll
                for (int ni = 1; ni < 4; ++ni)
                    r = fmaxf(r, fmaxf(fmaxf(s_acc[mi][ni][0], s_acc[mi][ni][1]),
                                       fmaxf(s_acc[mi][ni][2], s_acc[mi][ni][3])));
                rp[mi] = r;
                ok &= (r <= m_r[mi] + 8.f) ? 1 : 0;
            }
            if (!__all(ok)) {   // slow path: full row max across l4 lanes + rescale
#pragma unroll
                for (int mi = 0; mi < 2; ++mi) {
                    float r = rp[mi];
                    r = fmaxf(r, __shfl_xor(r, 16));
                    r = fmaxf(r, __shfl_xor(r, 32));
                    const float mnew = fmaxf(m_r[mi], r);
                    const float corr = hw_exp2(m_r[mi] - mnew);
                    m_r[mi] = mnew;
                    l_part[mi] *= corr;
#pragma unroll
                    for (int nd = 0; nd < 4; ++nd) acc_o[mi][nd] *= corr;
                }
            }

            // ---- exp2 + pack + PV per s; V^T fragments from LDS (slot-perm read) ----
#pragma unroll
            for (int s = 0; s < 2; ++s) {
                union { u32 w4[4]; bf16x8 v; } pw[2];
#pragma unroll
                for (int mi = 0; mi < 2; ++mi) {
                    f32x4 pa, pb;
#pragma unroll
                    for (int j = 0; j < 4; ++j) {
                        pa[j] = hw_exp2(s_acc[mi][2 * s + 0][j] - m_r[mi]);
                        pb[j] = hw_exp2(s_acc[mi][2 * s + 1][j] - m_r[mi]);
                    }
                    l_part[mi] += (pa[0] + pa[1]) + (pa[2] + pa[3])
                                + (pb[0] + pb[1]) + (pb[2] + pb[3]);
                    pw[mi].w4[0] = pack2bf(pa[0], pa[1]);
                    pw[mi].w4[1] = pack2bf(pa[2], pa[3]);
                    pw[mi].w4[2] = pack2bf(pb[0], pb[1]);
                    pw[mi].w4[3] = pack2bf(pb[2], pb[3]);
                }
                // V^T LDS read: row d = nd*16+l15; byte group0 at chunk s*4+(l4>>1),
                // group1 at chunk+2 (t offset +16); sub-offset (l4&1)*8; chunk ^= row&7.
                const int ch0 = s * 4 + (l4 >> 1);
                const int sub = (l4 & 1) * 8;
#pragma unroll
                for (int nd = 0; nd < 4; ++nd) {
                    const int d  = nd * 16 + l15;
                    const char* vrow = Vb + d * 128;
                    union { u16x4 h2[2]; bf16x8 v; } vbs;
                    vbs.h2[0] = *reinterpret_cast<const u16x4*>(
                        vrow + ((ch0 ^ (d & 7)) << 4) + sub);
                    vbs.h2[1] = *reinterpret_cast<const u16x4*>(
                        vrow + (((ch0 + 2) ^ (d & 7)) << 4) + sub);
#pragma unroll
                    for (int mi = 0; mi < 2; ++mi)
                        acc_o[mi][nd] = __builtin_amdgcn_mfma_f32_16x16x32_bf16(
                            vbs.v, pw[mi].v, acc_o[mi][nd], 0, 0, 0);
                }
            }
        }

        __syncthreads();   // next buffer staged (vmcnt drained) + this buffer's reads done
    }

    // ---- epilogue: finalize row sums (2 shfl), normalize, store (no merge) ----
#pragma unroll
    for (int mi = 0; mi < 2; ++mi) {
        float lp = l_part[mi];
        lp += __shfl_xor(lp, 16);
        lp += __shfl_xor(lp, 32);
        const float inv = 1.f / lp;
        const int q = q0w + mi * 16 + l15;
        const size_t rbase = (size_t)(b * GT_SEQ + q) * GC + h * GDH;
#pragma unroll
        for (int nd = 0; nd < 4; ++nd) {
            ushort4 ov;
            ov.x = f2bf(acc_o[mi][nd][0] * inv);
            ov.y = f2bf(acc_o[mi][nd][1] * inv);
            ov.z = f2bf(acc_o[mi][nd][2] * inv);
            ov.w = f2bf(acc_o[mi][nd][3] * inv);
            *reinterpret_cast<ushort4*>(&O[rbase + nd * 16 + l4 * 4]) = ov;
        }
    }
}

extern "C" void kernel_launch(void* const* d_in, const int* in_sizes, int n_in,
                              void* d_out, int out_size, void* d_ws, size_t ws_size,
                              hipStream_t stream) {
    (void)in_sizes; (void)n_in; (void)out_size; (void)ws_size;
    const float* x      = (const float*)d_in[0];
    const float* w_attn = (const float*)d_in[1];
    const float* b_attn = (const float*)d_in[2];
    const float* w_proj = (const float*)d_in[3];
    const float* b_proj = (const float*)d_in[4];
    float* out = (float*)d_out;

    unsigned short* xb  = (unsigned short*)d_ws;             // [4096][1024]
    unsigned short* wab = xb  + (size_t)GM * GC;             // [3072][1024]
    unsigned short* wpb = wab + (size_t)3 * GC * GC;         // [1024][1024]
    unsigned short* Qh  = wpb + (size_t)GC * GC;             // [32][2048][64]
    unsigned short* Kh  = Qh  + (size_t)4 * 1024 * 1024;
    unsigned short* Vh  = Kh  + (size_t)4 * 1024 * 1024;
    unsigned short* Vt  = Vh  + (size_t)4 * 1024 * 1024;     // [32][64][2048]
    unsigned short* aob = xb;   // reuse: xb dead after GEMM1

    // 0) fused casts (one launch): x(4M) | w_attn(3M) | w_proj(1M) = 8M elems
    cast3_f32_bf16<<<dim3(8192), dim3(256), 0, stream>>>(
        x, xb, GM * GC, w_attn, wab, 3 * GC * GC, w_proj, wpb);

    // 1) fused qkv projection -> Qh (scaled), Kh, Vh
    gemm_qkv<<<dim3(3 * GC / 128, GM / 128), dim3(256), 0, stream>>>(
        xb, wab, b_attn, Qh, Kh, Vh);

    // 1.5) V transpose -> Vt
    transpose_v<<<dim3(GT_SEQ / 64, GB * GH), dim3(256), 0, stream>>>(Vh, Vt);

    // 2) flash attention v8 (4-wave LDS-shared K/V) -> aob [B,T,C] bf16
    //    grid = 32 bh * 16 q-blocks = 512 blocks
    flash_attn_mfma8<<<dim3(512), dim3(256), 0, stream>>>(Qh, Kh, Vt, aob);

    // 3) out = aob @ w_proj^T + b_proj (f32)
    gemm_mfma_bt<<<dim3(GC / 128, GM / 128), dim3(256), 0, stream>>>(
        aob, wpb, b_proj, out, GM, GC, GC);
}

// Round 15
// 121.926 us; speedup vs baseline: 1.5894x; 1.1253x over previous
//
#include <hip/hip_runtime.h>
#include <math.h>

// Problem constants: B=2, T=2048, C=1024, H=16, Dh=64
#define GB 2
#define GT_SEQ 2048
#define GC 1024
#define GH 16
#define GDH 64
#define GM (GB * GT_SEQ)      // 4096 rows

typedef __attribute__((ext_vector_type(8))) short bf16x8;   // 8 bf16 = 4 VGPRs
typedef __attribute__((ext_vector_type(8))) unsigned short u16x8;
typedef __attribute__((ext_vector_type(4))) unsigned short u16x4;
typedef __attribute__((ext_vector_type(4))) float f32x4;
typedef unsigned int u32;

#define QSCALE 0.18033688f   // 0.125 * log2(e): QK^T lands in log2 domain

__device__ __forceinline__ unsigned short f2bf(float f) {   // RNE f32 -> bf16
    unsigned int u = __float_as_uint(f);
    u += 0x7FFFu + ((u >> 16) & 1u);
    return (unsigned short)(u >> 16);
}
__device__ __forceinline__ float bf2f(unsigned short u) {   // exact bf16 -> f32
    return __uint_as_float(((unsigned int)u) << 16);
}
__device__ __forceinline__ float hw_exp2(float x) {         // v_exp_f32
    return __builtin_amdgcn_exp2f(x);
}
// pack 2 f32 -> u32 of 2 bf16 (lo in low half); validated rounds 9-14
__device__ __forceinline__ u32 pack2bf(float lo, float hi) {
    return ((u32)f2bf(hi) << 16) | (u32)f2bf(lo);
}

// async global->LDS, 16B per lane; LDS dest is wave-uniform base (+lane*16 by HW)
#define GLOAD_LDS16(g, l) __builtin_amdgcn_global_load_lds( \
    (const __attribute__((address_space(1))) void*)(g),      \
    (__attribute__((address_space(3))) void*)(l), 16, 0, 0)

// swizzled fragment read: rows of 64 bf16 (128B = 8 chunks), chunk ^= (row&7)
__device__ __forceinline__ bf16x8 frag_ld(const char* base, int r, int kch) {
    return *reinterpret_cast<const bf16x8*>(base + r * 128 + ((kch ^ (r & 7)) << 4));
}

// ---------------- fused cast f32 -> bf16 (x | w_attn | w_proj, one launch) ----------------
__global__ __launch_bounds__(256) void cast3_f32_bf16(
    const float* __restrict__ a, unsigned short* __restrict__ oa, int na,
    const float* __restrict__ b, unsigned short* __restrict__ ob, int nb,
    const float* __restrict__ c, unsigned short* __restrict__ oc)
{
    const int i = (blockIdx.x * 256 + threadIdx.x) * 4;
    const float* src; unsigned short* dst; int off;
    if (i < na)            { src = a; dst = oa; off = i; }
    else if (i < na + nb)  { src = b; dst = ob; off = i - na; }
    else                   { src = c; dst = oc; off = i - na - nb; }
    const float4 v = *reinterpret_cast<const float4*>(&src[off]);
    ushort4 o;
    o.x = f2bf(v.x); o.y = f2bf(v.y); o.z = f2bf(v.z); o.w = f2bf(v.w);
    *reinterpret_cast<ushort4*>(&dst[off]) = o;
}

// ---------------- bf16 MFMA GEMM: C = A @ B^T + bias (validated rounds 2-14) ----------------
// Cb != null -> bf16 out; else f32 out to Cf.
__global__ __launch_bounds__(256) void gemm_mfma_bt(
    const unsigned short* __restrict__ A,   // [M][K] bf16
    const unsigned short* __restrict__ B,   // [N][K] bf16
    const float* __restrict__ bias,         // [N] f32
    float* __restrict__ Cf,                 // f32 out (or null)
    unsigned short* __restrict__ Cb,        // bf16 out (or null)
    int M, int N, int K)
{
    __shared__ char As[128 * 128];
    __shared__ char Bs[128 * 128];

    const int tid  = threadIdx.x;
    const int lane = tid & 63;
    const int w    = tid >> 6;
    const int wm   = w >> 1;
    const int wn   = w & 1;
    const int m0 = blockIdx.y * 128;
    const int n0 = blockIdx.x * 128;

    f32x4 acc[4][4];
#pragma unroll
    for (int i = 0; i < 4; ++i)
#pragma unroll
        for (int j = 0; j < 4; ++j) acc[i][j] = (f32x4){0.f, 0.f, 0.f, 0.f};

    const int wbase = (tid & ~63);

    for (int k0 = 0; k0 < K; k0 += 64) {
        const char* Ag = (const char*)(A + (size_t)m0 * K + k0);
        const char* Bg = (const char*)(B + (size_t)n0 * K + k0);
#pragma unroll
        for (int i = 0; i < 4; ++i) {
            const int c = i * 256 + tid;
            const int row = c >> 3, cin = c & 7;
            const size_t goff = (size_t)row * (K * 2) + (size_t)((cin ^ (row & 7)) << 4);
            GLOAD_LDS16(Ag + goff, As + (i * 256 + wbase) * 16);
            GLOAD_LDS16(Bg + goff, Bs + (i * 256 + wbase) * 16);
        }
        __syncthreads();

#pragma unroll
        for (int ks = 0; ks < 2; ++ks) {
            const int kch = ks * 4 + (lane >> 4);
            bf16x8 a[4], b[4];
#pragma unroll
            for (int mi = 0; mi < 4; ++mi)
                a[mi] = frag_ld(As, wm * 64 + mi * 16 + (lane & 15), kch);
#pragma unroll
            for (int ni = 0; ni < 4; ++ni)
                b[ni] = frag_ld(Bs, wn * 64 + ni * 16 + (lane & 15), kch);
#pragma unroll
            for (int mi = 0; mi < 4; ++mi)
#pragma unroll
                for (int ni = 0; ni < 4; ++ni)
                    acc[mi][ni] = __builtin_amdgcn_mfma_f32_16x16x32_bf16(
                        a[mi], b[ni], acc[mi][ni], 0, 0, 0);
        }
        __syncthreads();
    }

    const int lc  = lane & 15;
    const int lr4 = (lane >> 4) * 4;
#pragma unroll
    for (int ni = 0; ni < 4; ++ni) {
        const int gcol = n0 + wn * 64 + ni * 16 + lc;
        const float bv = bias[gcol];
#pragma unroll
        for (int mi = 0; mi < 4; ++mi) {
            const int grow0 = m0 + wm * 64 + mi * 16 + lr4;
#pragma unroll
            for (int j = 0; j < 4; ++j) {
                const float v = acc[mi][ni][j] + bv;
                if (Cb) Cb[(size_t)(grow0 + j) * N + gcol] = f2bf(v);
                else    Cf[(size_t)(grow0 + j) * N + gcol] = v;
            }
        }
    }
}

// ---------------- V transpose: qkvb[.][2C + h*64 + d] -> Vt[bh][d][t] ----------------
__global__ __launch_bounds__(256) void transpose_v(
    const unsigned short* __restrict__ qkvb, unsigned short* __restrict__ Vt)
{
    __shared__ unsigned short vt[64][72];
    const int tid = threadIdx.x;
    const int t0  = blockIdx.x * 64;
    const int bh  = blockIdx.y;
    const int b = bh >> 4, h = bh & 15;
    const unsigned short* src = qkvb + (size_t)(b * GT_SEQ) * (3 * GC) + 2 * GC + h * GDH;
    unsigned short* dstb = Vt + (size_t)bh * GDH * GT_SEQ;

#pragma unroll
    for (int i = 0; i < 2; ++i) {
        const int c = i * 256 + tid;
        const int tr = c >> 3, ch = c & 7;
        *reinterpret_cast<u16x8*>(&vt[tr][ch * 8]) =
            *reinterpret_cast<const u16x8*>(src + (size_t)(t0 + tr) * (3 * GC) + ch * 8);
    }
    __syncthreads();
#pragma unroll
    for (int i = 0; i < 2; ++i) {
        const int c = i * 256 + tid;
        const int d = c >> 3, ch = c & 7;
        u16x8 o;
#pragma unroll
        for (int e = 0; e < 8; ++e) o[e] = vt[ch * 8 + e][d];
        *reinterpret_cast<u16x8*>(dstb + (size_t)d * GT_SEQ + t0 + ch * 8) = o;
    }
}

// ---------------- flash attention v8b: 4-wave LDS-shared K/V; K/Q direct from qkvb ----------------
// Identical compute core to r14's validated v8; only source addressing changed:
// K staged from qkvb rows (stride 6144B — global_load_lds source is per-lane
// arbitrary), Q loaded from qkvb and scaled in-register once per block.
__global__ __launch_bounds__(256) void flash_attn_mfma8(
    const unsigned short* __restrict__ qkvb,  // [4096][3072] bf16: q|k|v
    const unsigned short* __restrict__ Vt,    // [32][64][2048]
    unsigned short* __restrict__ O)           // [4096][1024] bf16
{
    __shared__ __align__(16) char Ks[2][64 * 128];   // K tile: row k, 64 d bf16, swizzled
    __shared__ __align__(16) char Vs[2][64 * 128];   // V^T tile: row d, 64 t bf16, swizzled

    const int tid  = threadIdx.x;
    const int lane = tid & 63;
    const int w    = tid >> 6;               // wave 0..3
    const int l15  = lane & 15;
    const int l4   = lane >> 4;
    const int bid  = blockIdx.x;              // 0..511
    const int xcd  = bid & 7;
    const int rest = bid >> 3;                // 0..63
    const int bh   = xcd * 4 + (rest & 3);    // 0..31
    const int qb   = 15 - (rest >> 2);        // 0..15, heavy first
    const int b    = bh >> 4, h = bh & 15;
    const int q0w  = qb * 128 + w * 32;

    const unsigned short* hQ = qkvb + (size_t)(b * GT_SEQ) * (3 * GC) + h * GDH;
    const char* hKc = (const char*)(qkvb + (size_t)(b * GT_SEQ) * (3 * GC) + GC + h * GDH);
    const char* hVc = (const char*)(Vt + (size_t)bh * GDH * GT_SEQ);

    // Q fragments loaded from qkvb, scaled in-register (once per block)
    bf16x8 qf[2][2];
#pragma unroll
    for (int mi = 0; mi < 2; ++mi)
#pragma unroll
        for (int s = 0; s < 2; ++s) {
            bf16x8 v = *reinterpret_cast<const bf16x8*>(
                hQ + (size_t)(q0w + mi * 16 + l15) * (3 * GC) + s * 32 + l4 * 8);
#pragma unroll
            for (int e = 0; e < 8; ++e)
                v[e] = (short)f2bf(bf2f((unsigned short)v[e]) * QSCALE);
            qf[mi][s] = v;
        }

    f32x4 acc_o[2][4];
    float l_part[2];
    float m_r[2];
#pragma unroll
    for (int mi = 0; mi < 2; ++mi) {
        l_part[mi] = 0.f;
        m_r[mi] = -1e30f;
#pragma unroll
        for (int nd = 0; nd < 4; ++nd) acc_o[mi][nd] = (f32x4){0.f, 0.f, 0.f, 0.f};
    }

    const int nt = qb * 2 + 2;
    const int wbase16 = (tid & ~63) * 16;

    // stage tile t into buffer bb: source pre-swizzled, dest linear (rule 21)
    auto STAGE = [&](int bb, int t) {
        const int k0 = t * 64;
#pragma unroll
        for (int i = 0; i < 2; ++i) {
            const int c = i * 256 + tid;
            const int row = c >> 3, cin = c & 7;
            GLOAD_LDS16(hKc + (size_t)(k0 + row) * (3 * GC * 2) + ((cin ^ (row & 7)) << 4),
                        Ks[bb] + i * 4096 + wbase16);
            GLOAD_LDS16(hVc + (size_t)row * 4096 + (size_t)k0 * 2 + ((cin ^ (row & 7)) << 4),
                        Vs[bb] + i * 4096 + wbase16);
        }
    };

    STAGE(0, 0);
    __syncthreads();

    for (int t = 0; t < nt; ++t) {
        if (t + 1 < nt) STAGE((t + 1) & 1, t + 1);

        const int k0 = t * 64;
        const char* Kb = Ks[t & 1];
        const char* Vb = Vs[t & 1];

        if (k0 <= q0w + 31) {
            // ---- QK^T swapped: S^T = mfma(K, Q), K fragments from LDS ----
            f32x4 s_acc[2][4];
#pragma unroll
            for (int mi = 0; mi < 2; ++mi)
#pragma unroll
                for (int ni = 0; ni < 4; ++ni) s_acc[mi][ni] = (f32x4){0.f, 0.f, 0.f, 0.f};
#pragma unroll
            for (int s = 0; s < 2; ++s) {
                bf16x8 kf[4];
#pragma unroll
                for (int ni = 0; ni < 4; ++ni)
                    kf[ni] = frag_ld(Kb, ni * 16 + l15, s * 4 + l4);
#pragma unroll
                for (int ni = 0; ni < 4; ++ni)
#pragma unroll
                    for (int mi = 0; mi < 2; ++mi)
                        s_acc[mi][ni] = __builtin_amdgcn_mfma_f32_16x16x32_bf16(
                            kf[ni], qf[mi][s], s_acc[mi][ni], 0, 0, 0);
            }

            // ---- causal mask (partial tiles only): k > q -> -inf ----
            if (k0 + 63 > q0w) {
#pragma unroll
                for (int mi = 0; mi < 2; ++mi)
#pragma unroll
                    for (int ni = 0; ni < 4; ++ni)
#pragma unroll
                        for (int j = 0; j < 4; ++j)
                            if (k0 + ni * 16 + l4 * 4 + j > q0w + mi * 16 + l15)
                                s_acc[mi][ni][j] = -1e30f;
            }

            // ---- deferred-max: in-lane partial max, rare rescale ----
            float rp[2];
            int ok = 1;
#pragma unroll
            for (int mi = 0; mi < 2; ++mi) {
                float r = fmaxf(fmaxf(s_acc[mi][0][0], s_acc[mi][0][1]),
                                fmaxf(s_acc[mi][0][2], s_acc[mi][0][3]));
#pragma unroll
                for (int ni = 1; ni < 4; ++ni)
                    r = fmaxf(r, fmaxf(fmaxf(s_acc[mi][ni][0], s_acc[mi][ni][1]),
                                       fmaxf(s_acc[mi][ni][2], s_acc[mi][ni][3])));
                rp[mi] = r;
                ok &= (r <= m_r[mi] + 8.f) ? 1 : 0;
            }
            if (!__all(ok)) {
#pragma unroll
                for (int mi = 0; mi < 2; ++mi) {
                    float r = rp[mi];
                    r = fmaxf(r, __shfl_xor(r, 16));
                    r = fmaxf(r, __shfl_xor(r, 32));
                    const float mnew = fmaxf(m_r[mi], r);
                    const float corr = hw_exp2(m_r[mi] - mnew);
                    m_r[mi] = mnew;
                    l_part[mi] *= corr;
#pragma unroll
                    for (int nd = 0; nd < 4; ++nd) acc_o[mi][nd] *= corr;
                }
            }

            // ---- exp2 + pack + PV per s; V^T fragments from LDS (slot-perm read) ----
#pragma unroll
            for (int s = 0; s < 2; ++s) {
                union { u32 w4[4]; bf16x8 v; } pw[2];
#pragma unroll
                for (int mi = 0; mi < 2; ++mi) {
                    f32x4 pa, pb;
#pragma unroll
                    for (int j = 0; j < 4; ++j) {
                        pa[j] = hw_exp2(s_acc[mi][2 * s + 0][j] - m_r[mi]);
                        pb[j] = hw_exp2(s_acc[mi][2 * s + 1][j] - m_r[mi]);
                    }
                    l_part[mi] += (pa[0] + pa[1]) + (pa[2] + pa[3])
                                + (pb[0] + pb[1]) + (pb[2] + pb[3]);
                    pw[mi].w4[0] = pack2bf(pa[0], pa[1]);
                    pw[mi].w4[1] = pack2bf(pa[2], pa[3]);
                    pw[mi].w4[2] = pack2bf(pb[0], pb[1]);
                    pw[mi].w4[3] = pack2bf(pb[2], pb[3]);
                }
                const int ch0 = s * 4 + (l4 >> 1);
                const int sub = (l4 & 1) * 8;
#pragma unroll
                for (int nd = 0; nd < 4; ++nd) {
                    const int d  = nd * 16 + l15;
                    const char* vrow = Vb + d * 128;
                    union { u16x4 h2[2]; bf16x8 v; } vbs;
                    vbs.h2[0] = *reinterpret_cast<const u16x4*>(
                        vrow + ((ch0 ^ (d & 7)) << 4) + sub);
                    vbs.h2[1] = *reinterpret_cast<const u16x4*>(
                        vrow + (((ch0 + 2) ^ (d & 7)) << 4) + sub);
#pragma unroll
                    for (int mi = 0; mi < 2; ++mi)
                        acc_o[mi][nd] = __builtin_amdgcn_mfma_f32_16x16x32_bf16(
                            vbs.v, pw[mi].v, acc_o[mi][nd], 0, 0, 0);
                }
            }
        }

        __syncthreads();
    }

    // ---- epilogue: finalize row sums, normalize, store (no merge) ----
#pragma unroll
    for (int mi = 0; mi < 2; ++mi) {
        float lp = l_part[mi];
        lp += __shfl_xor(lp, 16);
        lp += __shfl_xor(lp, 32);
        const float inv = 1.f / lp;
        const int q = q0w + mi * 16 + l15;
        const size_t rbase = (size_t)(b * GT_SEQ + q) * GC + h * GDH;
#pragma unroll
        for (int nd = 0; nd < 4; ++nd) {
            ushort4 ov;
            ov.x = f2bf(acc_o[mi][nd][0] * inv);
            ov.y = f2bf(acc_o[mi][nd][1] * inv);
            ov.z = f2bf(acc_o[mi][nd][2] * inv);
            ov.w = f2bf(acc_o[mi][nd][3] * inv);
            *reinterpret_cast<ushort4*>(&O[rbase + nd * 16 + l4 * 4]) = ov;
        }
    }
}

extern "C" void kernel_launch(void* const* d_in, const int* in_sizes, int n_in,
                              void* d_out, int out_size, void* d_ws, size_t ws_size,
                              hipStream_t stream) {
    (void)in_sizes; (void)n_in; (void)out_size; (void)ws_size;
    const float* x      = (const float*)d_in[0];
    const float* w_attn = (const float*)d_in[1];
    const float* b_attn = (const float*)d_in[2];
    const float* w_proj = (const float*)d_in[3];
    const float* b_proj = (const float*)d_in[4];
    float* out = (float*)d_out;

    unsigned short* xb   = (unsigned short*)d_ws;            // [4096][1024]
    unsigned short* wab  = xb   + (size_t)GM * GC;           // [3072][1024]
    unsigned short* wpb  = wab  + (size_t)3 * GC * GC;       // [1024][1024]
    unsigned short* qkvb = wpb  + (size_t)GC * GC;           // [4096][3072]
    unsigned short* Vt   = qkvb + (size_t)GM * 3 * GC;       // [32][64][2048]
    unsigned short* aob  = xb;   // reuse: xb dead after GEMM1

    // 0) fused casts: x(4M) | w_attn(3M) | w_proj(1M) = 8M elems
    cast3_f32_bf16<<<dim3(8192), dim3(256), 0, stream>>>(
        x, xb, GM * GC, w_attn, wab, 3 * GC * GC, w_proj, wpb);

    // 1) qkv = x @ w_attn^T + b_attn (bf16, plain row-major epilogue)
    gemm_mfma_bt<<<dim3(3 * GC / 128, GM / 128), dim3(256), 0, stream>>>(
        xb, wab, b_attn, nullptr, qkvb, GM, 3 * GC, GC);

    // 1.5) V transpose from qkvb -> Vt
    transpose_v<<<dim3(GT_SEQ / 64, GB * GH), dim3(256), 0, stream>>>(qkvb, Vt);

    // 2) flash attention v8b (LDS-shared K/V; K/Q direct from qkvb) -> aob
    flash_attn_mfma8<<<dim3(512), dim3(256), 0, stream>>>(qkvb, Vt, aob);

    // 3) out = aob @ w_proj^T + b_proj (f32)
    gemm_mfma_bt<<<dim3(GC / 128, GM / 128), dim3(256), 0, stream>>>(
        aob, wpb, b_proj, out, nullptr, GM, GC, GC);
}

// Round 16
// 118.327 us; speedup vs baseline: 1.6378x; 1.0304x over previous
//
#include <hip/hip_runtime.h>
#include <math.h>

// Problem constants: B=2, T=2048, C=1024, H=16, Dh=64
#define GB 2
#define GT_SEQ 2048
#define GC 1024
#define GH 16
#define GDH 64
#define GM (GB * GT_SEQ)      // 4096 rows

typedef __attribute__((ext_vector_type(8))) short bf16x8;   // 8 bf16 = 4 VGPRs
typedef __attribute__((ext_vector_type(8))) unsigned short u16x8;
typedef __attribute__((ext_vector_type(4))) unsigned short u16x4;
typedef __attribute__((ext_vector_type(4))) float f32x4;
typedef unsigned int u32;

#define QSCALE 0.18033688f   // 0.125 * log2(e): QK^T lands in log2 domain

__device__ __forceinline__ unsigned short f2bf(float f) {   // RNE f32 -> bf16
    unsigned int u = __float_as_uint(f);
    u += 0x7FFFu + ((u >> 16) & 1u);
    return (unsigned short)(u >> 16);
}
__device__ __forceinline__ float bf2f(unsigned short u) {   // exact bf16 -> f32
    return __uint_as_float(((unsigned int)u) << 16);
}
__device__ __forceinline__ float hw_exp2(float x) {         // v_exp_f32
    return __builtin_amdgcn_exp2f(x);
}
// pack 2 f32 -> u32 of 2 bf16 (lo in low half); validated rounds 9-15
__device__ __forceinline__ u32 pack2bf(float lo, float hi) {
    return ((u32)f2bf(hi) << 16) | (u32)f2bf(lo);
}

// async global->LDS, 16B per lane; LDS dest is wave-uniform base (+lane*16 by HW)
#define GLOAD_LDS16(g, l) __builtin_amdgcn_global_load_lds( \
    (const __attribute__((address_space(1))) void*)(g),      \
    (__attribute__((address_space(3))) void*)(l), 16, 0, 0)

// swizzled fragment read: rows of 64 bf16 (128B = 8 chunks), chunk ^= (row&7)
__device__ __forceinline__ bf16x8 frag_ld(const char* base, int r, int kch) {
    return *reinterpret_cast<const bf16x8*>(base + r * 128 + ((kch ^ (r & 7)) << 4));
}

// ---------------- fused cast f32 -> bf16 (x | w_attn | w_proj, one launch) ----------------
__global__ __launch_bounds__(256) void cast3_f32_bf16(
    const float* __restrict__ a, unsigned short* __restrict__ oa, int na,
    const float* __restrict__ b, unsigned short* __restrict__ ob, int nb,
    const float* __restrict__ c, unsigned short* __restrict__ oc)
{
    const int i = (blockIdx.x * 256 + threadIdx.x) * 4;
    const float* src; unsigned short* dst; int off;
    if (i < na)            { src = a; dst = oa; off = i; }
    else if (i < na + nb)  { src = b; dst = ob; off = i - na; }
    else                   { src = c; dst = oc; off = i - na - nb; }
    const float4 v = *reinterpret_cast<const float4*>(&src[off]);
    ushort4 o;
    o.x = f2bf(v.x); o.y = f2bf(v.y); o.z = f2bf(v.z); o.w = f2bf(v.w);
    *reinterpret_cast<ushort4*>(&dst[off]) = o;
}

// ---------------- bf16 MFMA GEMM: C = A @ B^T + bias (validated rounds 2-15) ----------------
__global__ __launch_bounds__(256) void gemm_mfma_bt(
    const unsigned short* __restrict__ A,   // [M][K] bf16
    const unsigned short* __restrict__ B,   // [N][K] bf16
    const float* __restrict__ bias,         // [N] f32
    float* __restrict__ Cf,                 // f32 out (or null)
    unsigned short* __restrict__ Cb,        // bf16 out (or null)
    int M, int N, int K)
{
    __shared__ char As[128 * 128];
    __shared__ char Bs[128 * 128];

    const int tid  = threadIdx.x;
    const int lane = tid & 63;
    const int w    = tid >> 6;
    const int wm   = w >> 1;
    const int wn   = w & 1;
    const int m0 = blockIdx.y * 128;
    const int n0 = blockIdx.x * 128;

    f32x4 acc[4][4];
#pragma unroll
    for (int i = 0; i < 4; ++i)
#pragma unroll
        for (int j = 0; j < 4; ++j) acc[i][j] = (f32x4){0.f, 0.f, 0.f, 0.f};

    const int wbase = (tid & ~63);

    for (int k0 = 0; k0 < K; k0 += 64) {
        const char* Ag = (const char*)(A + (size_t)m0 * K + k0);
        const char* Bg = (const char*)(B + (size_t)n0 * K + k0);
#pragma unroll
        for (int i = 0; i < 4; ++i) {
            const int c = i * 256 + tid;
            const int row = c >> 3, cin = c & 7;
            const size_t goff = (size_t)row * (K * 2) + (size_t)((cin ^ (row & 7)) << 4);
            GLOAD_LDS16(Ag + goff, As + (i * 256 + wbase) * 16);
            GLOAD_LDS16(Bg + goff, Bs + (i * 256 + wbase) * 16);
        }
        __syncthreads();

#pragma unroll
        for (int ks = 0; ks < 2; ++ks) {
            const int kch = ks * 4 + (lane >> 4);
            bf16x8 a[4], b[4];
#pragma unroll
            for (int mi = 0; mi < 4; ++mi)
                a[mi] = frag_ld(As, wm * 64 + mi * 16 + (lane & 15), kch);
#pragma unroll
            for (int ni = 0; ni < 4; ++ni)
                b[ni] = frag_ld(Bs, wn * 64 + ni * 16 + (lane & 15), kch);
#pragma unroll
            for (int mi = 0; mi < 4; ++mi)
#pragma unroll
                for (int ni = 0; ni < 4; ++ni)
                    acc[mi][ni] = __builtin_amdgcn_mfma_f32_16x16x32_bf16(
                        a[mi], b[ni], acc[mi][ni], 0, 0, 0);
        }
        __syncthreads();
    }

    const int lc  = lane & 15;
    const int lr4 = (lane >> 4) * 4;
#pragma unroll
    for (int ni = 0; ni < 4; ++ni) {
        const int gcol = n0 + wn * 64 + ni * 16 + lc;
        const float bv = bias[gcol];
#pragma unroll
        for (int mi = 0; mi < 4; ++mi) {
            const int grow0 = m0 + wm * 64 + mi * 16 + lr4;
#pragma unroll
            for (int j = 0; j < 4; ++j) {
                const float v = acc[mi][ni][j] + bv;
                if (Cb) Cb[(size_t)(grow0 + j) * N + gcol] = f2bf(v);
                else    Cf[(size_t)(grow0 + j) * N + gcol] = v;
            }
        }
    }
}

// ---------------- V transpose: qkvb[.][2C + h*64 + d] -> Vt[bh][d][t] ----------------
__global__ __launch_bounds__(256) void transpose_v(
    const unsigned short* __restrict__ qkvb, unsigned short* __restrict__ Vt)
{
    __shared__ unsigned short vt[64][72];
    const int tid = threadIdx.x;
    const int t0  = blockIdx.x * 64;
    const int bh  = blockIdx.y;
    const int b = bh >> 4, h = bh & 15;
    const unsigned short* src = qkvb + (size_t)(b * GT_SEQ) * (3 * GC) + 2 * GC + h * GDH;
    unsigned short* dstb = Vt + (size_t)bh * GDH * GT_SEQ;

#pragma unroll
    for (int i = 0; i < 2; ++i) {
        const int c = i * 256 + tid;
        const int tr = c >> 3, ch = c & 7;
        *reinterpret_cast<u16x8*>(&vt[tr][ch * 8]) =
            *reinterpret_cast<const u16x8*>(src + (size_t)(t0 + tr) * (3 * GC) + ch * 8);
    }
    __syncthreads();
#pragma unroll
    for (int i = 0; i < 2; ++i) {
        const int c = i * 256 + tid;
        const int d = c >> 3, ch = c & 7;
        u16x8 o;
#pragma unroll
        for (int e = 0; e < 8; ++e) o[e] = vt[ch * 8 + e][d];
        *reinterpret_cast<u16x8*>(dstb + (size_t)d * GT_SEQ + t0 + ch * 8) = o;
    }
}

// ---------------- flash attention v9: 64-row q-blocks (4 waves x 16 rows) ----------------
// r15's validated v8b core with q-block halved: grid 1024 (= 4 blocks/CU), wave
// w owns rows qb*64 + w*16 .. +15 (mi dimension drops to 1). K/V staged once per
// block into double-buffered LDS (pre-swizzled source, linear dest). Single
// structural change vs r15 for attribution: supply 2 -> 4 blocks/CU.
__global__ __launch_bounds__(256) void flash_attn_mfma9(
    const unsigned short* __restrict__ qkvb,  // [4096][3072] bf16: q|k|v
    const unsigned short* __restrict__ Vt,    // [32][64][2048]
    unsigned short* __restrict__ O)           // [4096][1024] bf16
{
    __shared__ __align__(16) char Ks[2][64 * 128];   // K tile: row k, 64 d bf16, swizzled
    __shared__ __align__(16) char Vs[2][64 * 128];   // V^T tile: row d, 64 t bf16, swizzled

    const int tid  = threadIdx.x;
    const int lane = tid & 63;
    const int w    = tid >> 6;               // wave 0..3
    const int l15  = lane & 15;
    const int l4   = lane >> 4;
    const int bid  = blockIdx.x;              // 0..1023
    const int xcd  = bid & 7;
    const int rest = bid >> 3;                // 0..127
    const int bh   = xcd * 4 + (rest & 3);    // 0..31
    const int qb   = 31 - (rest >> 2);        // 0..31 (64-row blocks), heavy first
    const int b    = bh >> 4, h = bh & 15;
    const int q0w  = qb * 64 + w * 16;        // this wave's 16 q rows

    const unsigned short* hQ = qkvb + (size_t)(b * GT_SEQ) * (3 * GC) + h * GDH;
    const char* hKc = (const char*)(qkvb + (size_t)(b * GT_SEQ) * (3 * GC) + GC + h * GDH);
    const char* hVc = (const char*)(Vt + (size_t)bh * GDH * GT_SEQ);

    // Q fragments (scaled in-register once): qf[s], q row = l15, d = s*32+l4*8+e
    bf16x8 qf[2];
#pragma unroll
    for (int s = 0; s < 2; ++s) {
        bf16x8 v = *reinterpret_cast<const bf16x8*>(
            hQ + (size_t)(q0w + l15) * (3 * GC) + s * 32 + l4 * 8);
#pragma unroll
        for (int e = 0; e < 8; ++e)
            v[e] = (short)f2bf(bf2f((unsigned short)v[e]) * QSCALE);
        qf[s] = v;
    }

    f32x4 acc_o[4];
    float l_part = 0.f;
    float m_r = -1e30f;
#pragma unroll
    for (int nd = 0; nd < 4; ++nd) acc_o[nd] = (f32x4){0.f, 0.f, 0.f, 0.f};

    const int nt = qb + 1;                    // k-tiles covering q rows [qb*64, qb*64+64)
    const int wbase16 = (tid & ~63) * 16;

    // stage tile t into buffer bb: source pre-swizzled, dest linear (rule 21)
    auto STAGE = [&](int bb, int t) {
        const int k0 = t * 64;
#pragma unroll
        for (int i = 0; i < 2; ++i) {
            const int c = i * 256 + tid;
            const int row = c >> 3, cin = c & 7;
            GLOAD_LDS16(hKc + (size_t)(k0 + row) * (3 * GC * 2) + ((cin ^ (row & 7)) << 4),
                        Ks[bb] + i * 4096 + wbase16);
            GLOAD_LDS16(hVc + (size_t)row * 4096 + (size_t)k0 * 2 + ((cin ^ (row & 7)) << 4),
                        Vs[bb] + i * 4096 + wbase16);
        }
    };

    STAGE(0, 0);
    __syncthreads();

    for (int t = 0; t < nt; ++t) {
        if (t + 1 < nt) STAGE((t + 1) & 1, t + 1);

        const int k0 = t * 64;
        const char* Kb = Ks[t & 1];
        const char* Vb = Vs[t & 1];

        if (k0 <= q0w + 15) {   // wave-uniform skip of fully-masked tiles
            // ---- QK^T swapped: S^T = mfma(K, Q), K fragments from LDS ----
            // s_acc[ni]: S[q=l15][k = k0 + ni*16 + l4*4 + j]
            f32x4 s_acc[4];
#pragma unroll
            for (int ni = 0; ni < 4; ++ni) s_acc[ni] = (f32x4){0.f, 0.f, 0.f, 0.f};
#pragma unroll
            for (int s = 0; s < 2; ++s) {
                bf16x8 kf[4];
#pragma unroll
                for (int ni = 0; ni < 4; ++ni)
                    kf[ni] = frag_ld(Kb, ni * 16 + l15, s * 4 + l4);
#pragma unroll
                for (int ni = 0; ni < 4; ++ni)
                    s_acc[ni] = __builtin_amdgcn_mfma_f32_16x16x32_bf16(
                        kf[ni], qf[s], s_acc[ni], 0, 0, 0);
            }

            // ---- causal mask (partial tiles only): k > q -> -inf ----
            if (k0 + 63 > q0w) {
#pragma unroll
                for (int ni = 0; ni < 4; ++ni)
#pragma unroll
                    for (int j = 0; j < 4; ++j)
                        if (k0 + ni * 16 + l4 * 4 + j > q0w + l15)
                            s_acc[ni][j] = -1e30f;
            }

            // ---- deferred-max: in-lane partial max, rare rescale ----
            float r = fmaxf(fmaxf(s_acc[0][0], s_acc[0][1]),
                            fmaxf(s_acc[0][2], s_acc[0][3]));
#pragma unroll
            for (int ni = 1; ni < 4; ++ni)
                r = fmaxf(r, fmaxf(fmaxf(s_acc[ni][0], s_acc[ni][1]),
                                   fmaxf(s_acc[ni][2], s_acc[ni][3])));
            const int ok = (r <= m_r + 8.f) ? 1 : 0;
            if (!__all(ok)) {
                r = fmaxf(r, __shfl_xor(r, 16));
                r = fmaxf(r, __shfl_xor(r, 32));
                const float mnew = fmaxf(m_r, r);
                const float corr = hw_exp2(m_r - mnew);
                m_r = mnew;
                l_part *= corr;
#pragma unroll
                for (int nd = 0; nd < 4; ++nd) acc_o[nd] *= corr;
            }

            // ---- exp2 + pack + PV per s; V^T fragments from LDS (slot-perm read) ----
#pragma unroll
            for (int s = 0; s < 2; ++s) {
                union { u32 w4[4]; bf16x8 v; } pw;
                {
                    f32x4 pa, pb;
#pragma unroll
                    for (int j = 0; j < 4; ++j) {
                        pa[j] = hw_exp2(s_acc[2 * s + 0][j] - m_r);
                        pb[j] = hw_exp2(s_acc[2 * s + 1][j] - m_r);
                    }
                    l_part += (pa[0] + pa[1]) + (pa[2] + pa[3])
                            + (pb[0] + pb[1]) + (pb[2] + pb[3]);
                    pw.w4[0] = pack2bf(pa[0], pa[1]);
                    pw.w4[1] = pack2bf(pa[2], pa[3]);
                    pw.w4[2] = pack2bf(pb[0], pb[1]);
                    pw.w4[3] = pack2bf(pb[2], pb[3]);
                }
                const int ch0 = s * 4 + (l4 >> 1);
                const int sub = (l4 & 1) * 8;
#pragma unroll
                for (int nd = 0; nd < 4; ++nd) {
                    const int d  = nd * 16 + l15;
                    const char* vrow = Vb + d * 128;
                    union { u16x4 h2[2]; bf16x8 v; } vbs;
                    vbs.h2[0] = *reinterpret_cast<const u16x4*>(
                        vrow + ((ch0 ^ (d & 7)) << 4) + sub);
                    vbs.h2[1] = *reinterpret_cast<const u16x4*>(
                        vrow + (((ch0 + 2) ^ (d & 7)) << 4) + sub);
                    acc_o[nd] = __builtin_amdgcn_mfma_f32_16x16x32_bf16(
                        vbs.v, pw.v, acc_o[nd], 0, 0, 0);
                }
            }
        }

        __syncthreads();
    }

    // ---- epilogue: finalize row sum, normalize, store (no merge) ----
    {
        float lp = l_part;
        lp += __shfl_xor(lp, 16);
        lp += __shfl_xor(lp, 32);
        const float inv = 1.f / lp;
        const int q = q0w + l15;
        const size_t rbase = (size_t)(b * GT_SEQ + q) * GC + h * GDH;
#pragma unroll
        for (int nd = 0; nd < 4; ++nd) {
            ushort4 ov;
            ov.x = f2bf(acc_o[nd][0] * inv);
            ov.y = f2bf(acc_o[nd][1] * inv);
            ov.z = f2bf(acc_o[nd][2] * inv);
            ov.w = f2bf(acc_o[nd][3] * inv);
            *reinterpret_cast<ushort4*>(&O[rbase + nd * 16 + l4 * 4]) = ov;
        }
    }
}

extern "C" void kernel_launch(void* const* d_in, const int* in_sizes, int n_in,
                              void* d_out, int out_size, void* d_ws, size_t ws_size,
                              hipStream_t stream) {
    (void)in_sizes; (void)n_in; (void)out_size; (void)ws_size;
    const float* x      = (const float*)d_in[0];
    const float* w_attn = (const float*)d_in[1];
    const float* b_attn = (const float*)d_in[2];
    const float* w_proj = (const float*)d_in[3];
    const float* b_proj = (const float*)d_in[4];
    float* out = (float*)d_out;

    unsigned short* xb   = (unsigned short*)d_ws;            // [4096][1024]
    unsigned short* wab  = xb   + (size_t)GM * GC;           // [3072][1024]
    unsigned short* wpb  = wab  + (size_t)3 * GC * GC;       // [1024][1024]
    unsigned short* qkvb = wpb  + (size_t)GC * GC;           // [4096][3072]
    unsigned short* Vt   = qkvb + (size_t)GM * 3 * GC;       // [32][64][2048]
    unsigned short* aob  = xb;   // reuse: xb dead after GEMM1

    // 0) fused casts: x(4M) | w_attn(3M) | w_proj(1M) = 8M elems
    cast3_f32_bf16<<<dim3(8192), dim3(256), 0, stream>>>(
        x, xb, GM * GC, w_attn, wab, 3 * GC * GC, w_proj, wpb);

    // 1) qkv = x @ w_attn^T + b_attn (bf16, plain row-major epilogue)
    gemm_mfma_bt<<<dim3(3 * GC / 128, GM / 128), dim3(256), 0, stream>>>(
        xb, wab, b_attn, nullptr, qkvb, GM, 3 * GC, GC);

    // 1.5) V transpose from qkvb -> Vt
    transpose_v<<<dim3(GT_SEQ / 64, GB * GH), dim3(256), 0, stream>>>(qkvb, Vt);

    // 2) flash attention v9 (64-row q-blocks, 4 blocks/CU) -> aob
    //    grid = 32 bh * 32 q-blocks = 1024
    flash_attn_mfma9<<<dim3(1024), dim3(256), 0, stream>>>(qkvb, Vt, aob);

    // 3) out = aob @ w_proj^T + b_proj (f32)
    gemm_mfma_bt<<<dim3(GC / 128, GM / 128), dim3(256), 0, stream>>>(
        aob, wpb, b_proj, out, nullptr, GM, GC, GC);
}

// Round 17
// 116.277 us; speedup vs baseline: 1.6666x; 1.0176x over previous
//
#include <hip/hip_runtime.h>
#include <hip/hip_bf16.h>
#include <math.h>

// Problem constants: B=2, T=2048, C=1024, H=16, Dh=64
#define GB 2
#define GT_SEQ 2048
#define GC 1024
#define GH 16
#define GDH 64
#define GM (GB * GT_SEQ)      // 4096 rows

typedef __attribute__((ext_vector_type(8))) short bf16x8;   // 8 bf16 = 4 VGPRs
typedef __attribute__((ext_vector_type(8))) unsigned short u16x8;
typedef __attribute__((ext_vector_type(4))) unsigned short u16x4;
typedef __attribute__((ext_vector_type(4))) float f32x4;
typedef unsigned int u32;

#define QSCALE 0.18033688f   // 0.125 * log2(e): QK^T lands in log2 domain

__device__ __forceinline__ unsigned short f2bf(float f) {   // RNE f32 -> bf16
    unsigned int u = __float_as_uint(f);
    u += 0x7FFFu + ((u >> 16) & 1u);
    return (unsigned short)(u >> 16);
}
__device__ __forceinline__ float bf2f(unsigned short u) {   // exact bf16 -> f32
    return __uint_as_float(((unsigned int)u) << 16);
}
__device__ __forceinline__ float hw_exp2(float x) {         // v_exp_f32
    return __builtin_amdgcn_exp2f(x);
}
// pack 2 f32 -> u32 of 2 bf16 (lo in low half); compiler emits v_cvt_pk_bf16_f32.
// Numerics validated r11 (same slot mapping, passed absmax 0.0156).
__device__ __forceinline__ u32 pk_bf16(float lo, float hi) {
    __hip_bfloat162 h = __float22bfloat162_rn(make_float2(lo, hi));
    return *reinterpret_cast<u32*>(&h);
}

// async global->LDS, 16B per lane; LDS dest is wave-uniform base (+lane*16 by HW)
#define GLOAD_LDS16(g, l) __builtin_amdgcn_global_load_lds( \
    (const __attribute__((address_space(1))) void*)(g),      \
    (__attribute__((address_space(3))) void*)(l), 16, 0, 0)

// swizzled fragment read: rows of 64 bf16 (128B = 8 chunks), chunk ^= (row&7)
__device__ __forceinline__ bf16x8 frag_ld(const char* base, int r, int kch) {
    return *reinterpret_cast<const bf16x8*>(base + r * 128 + ((kch ^ (r & 7)) << 4));
}

// ---------------- fused cast f32 -> bf16 (x | w_attn | w_proj, one launch) ----------------
__global__ __launch_bounds__(256) void cast3_f32_bf16(
    const float* __restrict__ a, unsigned short* __restrict__ oa, int na,
    const float* __restrict__ b, unsigned short* __restrict__ ob, int nb,
    const float* __restrict__ c, unsigned short* __restrict__ oc)
{
    const int i = (blockIdx.x * 256 + threadIdx.x) * 4;
    const float* src; unsigned short* dst; int off;
    if (i < na)            { src = a; dst = oa; off = i; }
    else if (i < na + nb)  { src = b; dst = ob; off = i - na; }
    else                   { src = c; dst = oc; off = i - na - nb; }
    const float4 v = *reinterpret_cast<const float4*>(&src[off]);
    ushort4 o;
    o.x = f2bf(v.x); o.y = f2bf(v.y); o.z = f2bf(v.z); o.w = f2bf(v.w);
    *reinterpret_cast<ushort4*>(&dst[off]) = o;
}

// ---------------- bf16 MFMA GEMM: C = A @ B^T + bias (validated rounds 2-16) ----------------
// XCD-swizzled linearized block id (T1): grids must have nwg % 8 == 0.
__global__ __launch_bounds__(256) void gemm_mfma_bt(
    const unsigned short* __restrict__ A,   // [M][K] bf16
    const unsigned short* __restrict__ B,   // [N][K] bf16
    const float* __restrict__ bias,         // [N] f32
    float* __restrict__ Cf,                 // f32 out (or null)
    unsigned short* __restrict__ Cb,        // bf16 out (or null)
    int M, int N, int K)
{
    __shared__ char As[128 * 128];
    __shared__ char Bs[128 * 128];

    const int tid  = threadIdx.x;
    const int lane = tid & 63;
    const int w    = tid >> 6;
    const int wm   = w >> 1;
    const int wn   = w & 1;

    // XCD swizzle: consecutive swz ids stay on one XCD -> B-panel L2 reuse
    const int gx  = gridDim.x;
    const int lid = blockIdx.y * gx + blockIdx.x;
    const int nwg = gx * gridDim.y;
    const int cpx = nwg >> 3;                 // nwg % 8 == 0 (768, 256)
    const int swz = (lid & 7) * cpx + (lid >> 3);
    const int m0 = (swz / gx) * 128;
    const int n0 = (swz % gx) * 128;

    f32x4 acc[4][4];
#pragma unroll
    for (int i = 0; i < 4; ++i)
#pragma unroll
        for (int j = 0; j < 4; ++j) acc[i][j] = (f32x4){0.f, 0.f, 0.f, 0.f};

    const int wbase = (tid & ~63);

    for (int k0 = 0; k0 < K; k0 += 64) {
        const char* Ag = (const char*)(A + (size_t)m0 * K + k0);
        const char* Bg = (const char*)(B + (size_t)n0 * K + k0);
#pragma unroll
        for (int i = 0; i < 4; ++i) {
            const int c = i * 256 + tid;
            const int row = c >> 3, cin = c & 7;
            const size_t goff = (size_t)row * (K * 2) + (size_t)((cin ^ (row & 7)) << 4);
            GLOAD_LDS16(Ag + goff, As + (i * 256 + wbase) * 16);
            GLOAD_LDS16(Bg + goff, Bs + (i * 256 + wbase) * 16);
        }
        __syncthreads();

#pragma unroll
        for (int ks = 0; ks < 2; ++ks) {
            const int kch = ks * 4 + (lane >> 4);
            bf16x8 a[4], b[4];
#pragma unroll
            for (int mi = 0; mi < 4; ++mi)
                a[mi] = frag_ld(As, wm * 64 + mi * 16 + (lane & 15), kch);
#pragma unroll
            for (int ni = 0; ni < 4; ++ni)
                b[ni] = frag_ld(Bs, wn * 64 + ni * 16 + (lane & 15), kch);
#pragma unroll
            for (int mi = 0; mi < 4; ++mi)
#pragma unroll
                for (int ni = 0; ni < 4; ++ni)
                    acc[mi][ni] = __builtin_amdgcn_mfma_f32_16x16x32_bf16(
                        a[mi], b[ni], acc[mi][ni], 0, 0, 0);
        }
        __syncthreads();
    }

    const int lc  = lane & 15;
    const int lr4 = (lane >> 4) * 4;
#pragma unroll
    for (int ni = 0; ni < 4; ++ni) {
        const int gcol = n0 + wn * 64 + ni * 16 + lc;
        const float bv = bias[gcol];
#pragma unroll
        for (int mi = 0; mi < 4; ++mi) {
            const int grow0 = m0 + wm * 64 + mi * 16 + lr4;
#pragma unroll
            for (int j = 0; j < 4; ++j) {
                const float v = acc[mi][ni][j] + bv;
                if (Cb) Cb[(size_t)(grow0 + j) * N + gcol] = f2bf(v);
                else    Cf[(size_t)(grow0 + j) * N + gcol] = v;
            }
        }
    }
}

// ---------------- V transpose: qkvb[.][2C + h*64 + d] -> Vt[bh][d][t] ----------------
__global__ __launch_bounds__(256) void transpose_v(
    const unsigned short* __restrict__ qkvb, unsigned short* __restrict__ Vt)
{
    __shared__ unsigned short vt[64][72];
    const int tid = threadIdx.x;
    const int t0  = blockIdx.x * 64;
    const int bh  = blockIdx.y;
    const int b = bh >> 4, h = bh & 15;
    const unsigned short* src = qkvb + (size_t)(b * GT_SEQ) * (3 * GC) + 2 * GC + h * GDH;
    unsigned short* dstb = Vt + (size_t)bh * GDH * GT_SEQ;

#pragma unroll
    for (int i = 0; i < 2; ++i) {
        const int c = i * 256 + tid;
        const int tr = c >> 3, ch = c & 7;
        *reinterpret_cast<u16x8*>(&vt[tr][ch * 8]) =
            *reinterpret_cast<const u16x8*>(src + (size_t)(t0 + tr) * (3 * GC) + ch * 8);
    }
    __syncthreads();
#pragma unroll
    for (int i = 0; i < 2; ++i) {
        const int c = i * 256 + tid;
        const int d = c >> 3, ch = c & 7;
        u16x8 o;
#pragma unroll
        for (int e = 0; e < 8; ++e) o[e] = vt[ch * 8 + e][d];
        *reinterpret_cast<u16x8*>(dstb + (size_t)d * GT_SEQ + t0 + ch * 8) = o;
    }
}

// ---------------- flash attention v9b: r16 core + ones-MFMA l + cvt_pk pack ----------------
// Changes vs r16 (each numerically validated in passed rounds):
//  - row sum via acc_l = mfma(ones_A, P): kills 14 VALU adds/tile + epilogue shfls (r9-r11)
//  - pk_bf16 (compiler v_cvt_pk_bf16_f32) replaces 7-op bit pack (numerics r11)
__global__ __launch_bounds__(256) void flash_attn_mfma9(
    const unsigned short* __restrict__ qkvb,  // [4096][3072] bf16: q|k|v
    const unsigned short* __restrict__ Vt,    // [32][64][2048]
    unsigned short* __restrict__ O)           // [4096][1024] bf16
{
    __shared__ __align__(16) char Ks[2][64 * 128];   // K tile: row k, 64 d bf16, swizzled
    __shared__ __align__(16) char Vs[2][64 * 128];   // V^T tile: row d, 64 t bf16, swizzled

    const int tid  = threadIdx.x;
    const int lane = tid & 63;
    const int w    = tid >> 6;               // wave 0..3
    const int l15  = lane & 15;
    const int l4   = lane >> 4;
    const int bid  = blockIdx.x;              // 0..1023
    const int xcd  = bid & 7;
    const int rest = bid >> 3;                // 0..127
    const int bh   = xcd * 4 + (rest & 3);    // 0..31
    const int qb   = 31 - (rest >> 2);        // 0..31 (64-row blocks), heavy first
    const int b    = bh >> 4, h = bh & 15;
    const int q0w  = qb * 64 + w * 16;        // this wave's 16 q rows

    const unsigned short* hQ = qkvb + (size_t)(b * GT_SEQ) * (3 * GC) + h * GDH;
    const char* hKc = (const char*)(qkvb + (size_t)(b * GT_SEQ) * (3 * GC) + GC + h * GDH);
    const char* hVc = (const char*)(Vt + (size_t)bh * GDH * GT_SEQ);

    // all-ones A-fragment: acc_l = mfma(ones, P) -> D[r][q] = l_q in every reg
    bf16x8 ones_a;
#pragma unroll
    for (int e = 0; e < 8; ++e) ones_a[e] = (short)0x3F80;

    // Q fragments (scaled in-register once): qf[s], q row = l15, d = s*32+l4*8+e
    bf16x8 qf[2];
#pragma unroll
    for (int s = 0; s < 2; ++s) {
        bf16x8 v = *reinterpret_cast<const bf16x8*>(
            hQ + (size_t)(q0w + l15) * (3 * GC) + s * 32 + l4 * 8);
#pragma unroll
        for (int e = 0; e < 8; ++e)
            v[e] = (short)f2bf(bf2f((unsigned short)v[e]) * QSCALE);
        qf[s] = v;
    }

    f32x4 acc_o[4];
    f32x4 acc_l = (f32x4){0.f, 0.f, 0.f, 0.f};
    float m_r = -1e30f;
#pragma unroll
    for (int nd = 0; nd < 4; ++nd) acc_o[nd] = (f32x4){0.f, 0.f, 0.f, 0.f};

    const int nt = qb + 1;                    // k-tiles covering q rows [qb*64, qb*64+64)
    const int wbase16 = (tid & ~63) * 16;

    // stage tile t into buffer bb: source pre-swizzled, dest linear (rule 21)
    auto STAGE = [&](int bb, int t) {
        const int k0 = t * 64;
#pragma unroll
        for (int i = 0; i < 2; ++i) {
            const int c = i * 256 + tid;
            const int row = c >> 3, cin = c & 7;
            GLOAD_LDS16(hKc + (size_t)(k0 + row) * (3 * GC * 2) + ((cin ^ (row & 7)) << 4),
                        Ks[bb] + i * 4096 + wbase16);
            GLOAD_LDS16(hVc + (size_t)row * 4096 + (size_t)k0 * 2 + ((cin ^ (row & 7)) << 4),
                        Vs[bb] + i * 4096 + wbase16);
        }
    };

    STAGE(0, 0);
    __syncthreads();

    for (int t = 0; t < nt; ++t) {
        if (t + 1 < nt) STAGE((t + 1) & 1, t + 1);

        const int k0 = t * 64;
        const char* Kb = Ks[t & 1];
        const char* Vb = Vs[t & 1];

        if (k0 <= q0w + 15) {   // wave-uniform skip of fully-masked tiles
            // ---- QK^T swapped: S^T = mfma(K, Q), K fragments from LDS ----
            f32x4 s_acc[4];
#pragma unroll
            for (int ni = 0; ni < 4; ++ni) s_acc[ni] = (f32x4){0.f, 0.f, 0.f, 0.f};
#pragma unroll
            for (int s = 0; s < 2; ++s) {
                bf16x8 kf[4];
#pragma unroll
                for (int ni = 0; ni < 4; ++ni)
                    kf[ni] = frag_ld(Kb, ni * 16 + l15, s * 4 + l4);
#pragma unroll
                for (int ni = 0; ni < 4; ++ni)
                    s_acc[ni] = __builtin_amdgcn_mfma_f32_16x16x32_bf16(
                        kf[ni], qf[s], s_acc[ni], 0, 0, 0);
            }

            // ---- causal mask (partial tiles only): k > q -> -inf ----
            if (k0 + 63 > q0w) {
#pragma unroll
                for (int ni = 0; ni < 4; ++ni)
#pragma unroll
                    for (int j = 0; j < 4; ++j)
                        if (k0 + ni * 16 + l4 * 4 + j > q0w + l15)
                            s_acc[ni][j] = -1e30f;
            }

            // ---- deferred-max: in-lane partial max, rare rescale ----
            float r = fmaxf(fmaxf(s_acc[0][0], s_acc[0][1]),
                            fmaxf(s_acc[0][2], s_acc[0][3]));
#pragma unroll
            for (int ni = 1; ni < 4; ++ni)
                r = fmaxf(r, fmaxf(fmaxf(s_acc[ni][0], s_acc[ni][1]),
                                   fmaxf(s_acc[ni][2], s_acc[ni][3])));
            const int ok = (r <= m_r + 8.f) ? 1 : 0;
            if (!__all(ok)) {
                r = fmaxf(r, __shfl_xor(r, 16));
                r = fmaxf(r, __shfl_xor(r, 32));
                const float mnew = fmaxf(m_r, r);
                const float corr = hw_exp2(m_r - mnew);
                m_r = mnew;
                acc_l *= corr;
#pragma unroll
                for (int nd = 0; nd < 4; ++nd) acc_o[nd] *= corr;
            }

            // ---- exp2 + cvt_pk + PV per s; l via ones-MFMA ----
#pragma unroll
            for (int s = 0; s < 2; ++s) {
                union { u32 w4[4]; bf16x8 v; } pw;
                {
                    f32x4 pa, pb;
#pragma unroll
                    for (int j = 0; j < 4; ++j) {
                        pa[j] = hw_exp2(s_acc[2 * s + 0][j] - m_r);
                        pb[j] = hw_exp2(s_acc[2 * s + 1][j] - m_r);
                    }
                    pw.w4[0] = pk_bf16(pa[0], pa[1]);
                    pw.w4[1] = pk_bf16(pa[2], pa[3]);
                    pw.w4[2] = pk_bf16(pb[0], pb[1]);
                    pw.w4[3] = pk_bf16(pb[2], pb[3]);
                }
                acc_l = __builtin_amdgcn_mfma_f32_16x16x32_bf16(
                    ones_a, pw.v, acc_l, 0, 0, 0);
                const int ch0 = s * 4 + (l4 >> 1);
                const int sub = (l4 & 1) * 8;
#pragma unroll
                for (int nd = 0; nd < 4; ++nd) {
                    const int d  = nd * 16 + l15;
                    const char* vrow = Vb + d * 128;
                    union { u16x4 h2[2]; bf16x8 v; } vbs;
                    vbs.h2[0] = *reinterpret_cast<const u16x4*>(
                        vrow + ((ch0 ^ (d & 7)) << 4) + sub);
                    vbs.h2[1] = *reinterpret_cast<const u16x4*>(
                        vrow + (((ch0 + 2) ^ (d & 7)) << 4) + sub);
                    acc_o[nd] = __builtin_amdgcn_mfma_f32_16x16x32_bf16(
                        vbs.v, pw.v, acc_o[nd], 0, 0, 0);
                }
            }
        }

        __syncthreads();
    }

    // ---- epilogue: l = acc_l[0] (same value in all regs/rows), normalize, store ----
    {
        const float inv = 1.f / acc_l[0];
        const int q = q0w + l15;
        const size_t rbase = (size_t)(b * GT_SEQ + q) * GC + h * GDH;
#pragma unroll
        for (int nd = 0; nd < 4; ++nd) {
            ushort4 ov;
            ov.x = f2bf(acc_o[nd][0] * inv);
            ov.y = f2bf(acc_o[nd][1] * inv);
            ov.z = f2bf(acc_o[nd][2] * inv);
            ov.w = f2bf(acc_o[nd][3] * inv);
            *reinterpret_cast<ushort4*>(&O[rbase + nd * 16 + l4 * 4]) = ov;
        }
    }
}

extern "C" void kernel_launch(void* const* d_in, const int* in_sizes, int n_in,
                              void* d_out, int out_size, void* d_ws, size_t ws_size,
                              hipStream_t stream) {
    (void)in_sizes; (void)n_in; (void)out_size; (void)ws_size;
    const float* x      = (const float*)d_in[0];
    const float* w_attn = (const float*)d_in[1];
    const float* b_attn = (const float*)d_in[2];
    const float* w_proj = (const float*)d_in[3];
    const float* b_proj = (const float*)d_in[4];
    float* out = (float*)d_out;

    unsigned short* xb   = (unsigned short*)d_ws;            // [4096][1024]
    unsigned short* wab  = xb   + (size_t)GM * GC;           // [3072][1024]
    unsigned short* wpb  = wab  + (size_t)3 * GC * GC;       // [1024][1024]
    unsigned short* qkvb = wpb  + (size_t)GC * GC;           // [4096][3072]
    unsigned short* Vt   = qkvb + (size_t)GM * 3 * GC;       // [32][64][2048]
    unsigned short* aob  = xb;   // reuse: xb dead after GEMM1

    // 0) fused casts: x(4M) | w_attn(3M) | w_proj(1M) = 8M elems
    cast3_f32_bf16<<<dim3(8192), dim3(256), 0, stream>>>(
        x, xb, GM * GC, w_attn, wab, 3 * GC * GC, w_proj, wpb);

    // 1) qkv = x @ w_attn^T + b_attn (bf16), grid 24x32 = 768 (%8==0 for swizzle)
    gemm_mfma_bt<<<dim3(3 * GC / 128, GM / 128), dim3(256), 0, stream>>>(
        xb, wab, b_attn, nullptr, qkvb, GM, 3 * GC, GC);

    // 1.5) V transpose from qkvb -> Vt
    transpose_v<<<dim3(GT_SEQ / 64, GB * GH), dim3(256), 0, stream>>>(qkvb, Vt);

    // 2) flash attention v9b -> aob
    flash_attn_mfma9<<<dim3(1024), dim3(256), 0, stream>>>(qkvb, Vt, aob);

    // 3) out = aob @ w_proj^T + b_proj (f32), grid 8x32 = 256 (%8==0)
    gemm_mfma_bt<<<dim3(GC / 128, GM / 128), dim3(256), 0, stream>>>(
        aob, wpb, b_proj, out, nullptr, GM, GC, GC);
}

// Round 18
// 113.251 us; speedup vs baseline: 1.7112x; 1.0267x over previous
//
#include <hip/hip_runtime.h>
#include <hip/hip_bf16.h>
#include <math.h>

// Problem constants: B=2, T=2048, C=1024, H=16, Dh=64
#define GB 2
#define GT_SEQ 2048
#define GC 1024
#define GH 16
#define GDH 64
#define GM (GB * GT_SEQ)      // 4096 rows

typedef __attribute__((ext_vector_type(8))) short bf16x8;   // 8 bf16 = 4 VGPRs
typedef __attribute__((ext_vector_type(8))) unsigned short u16x8;
typedef __attribute__((ext_vector_type(4))) float f32x4;
typedef unsigned int u32;

#define QSCALE 0.18033688f   // 0.125 * log2(e): QK^T lands in log2 domain

__device__ __forceinline__ unsigned short f2bf(float f) {   // RNE f32 -> bf16
    unsigned int u = __float_as_uint(f);
    u += 0x7FFFu + ((u >> 16) & 1u);
    return (unsigned short)(u >> 16);
}
__device__ __forceinline__ float bf2f(unsigned short u) {   // exact bf16 -> f32
    return __uint_as_float(((unsigned int)u) << 16);
}
__device__ __forceinline__ float hw_exp2(float x) {         // v_exp_f32
    return __builtin_amdgcn_exp2f(x);
}
// pack 2 f32 -> u32 of 2 bf16 (lo in low half); compiler emits v_cvt_pk_bf16_f32
__device__ __forceinline__ u32 pk_bf16(float lo, float hi) {
    __hip_bfloat162 h = __float22bfloat162_rn(make_float2(lo, hi));
    return *reinterpret_cast<u32*>(&h);
}

// async global->LDS, 16B per lane; LDS dest is wave-uniform base (+lane*16 by HW)
#define GLOAD_LDS16(g, l) __builtin_amdgcn_global_load_lds( \
    (const __attribute__((address_space(1))) void*)(g),      \
    (__attribute__((address_space(3))) void*)(l), 16, 0, 0)

// swizzled fragment read: rows of 64 bf16 (128B = 8 chunks), chunk ^= (row&7)
__device__ __forceinline__ bf16x8 frag_ld(const char* base, int r, int kch) {
    return *reinterpret_cast<const bf16x8*>(base + r * 128 + ((kch ^ (r & 7)) << 4));
}

// ---------------- fused cast f32 -> bf16 (x | w_attn | w_proj, one launch) ----------------
__global__ __launch_bounds__(256) void cast3_f32_bf16(
    const float* __restrict__ a, unsigned short* __restrict__ oa, int na,
    const float* __restrict__ b, unsigned short* __restrict__ ob, int nb,
    const float* __restrict__ c, unsigned short* __restrict__ oc)
{
    const int i = (blockIdx.x * 256 + threadIdx.x) * 4;
    const float* src; unsigned short* dst; int off;
    if (i < na)            { src = a; dst = oa; off = i; }
    else if (i < na + nb)  { src = b; dst = ob; off = i - na; }
    else                   { src = c; dst = oc; off = i - na - nb; }
    const float4 v = *reinterpret_cast<const float4*>(&src[off]);
    ushort4 o;
    o.x = f2bf(v.x); o.y = f2bf(v.y); o.z = f2bf(v.z); o.w = f2bf(v.w);
    *reinterpret_cast<ushort4*>(&dst[off]) = o;
}

// ---------------- bf16 MFMA GEMM: C = A @ B^T + bias (validated rounds 2-17) ----------------
// XCD-swizzled linearized block id (T1): grids must have nwg % 8 == 0.
__global__ __launch_bounds__(256) void gemm_mfma_bt(
    const unsigned short* __restrict__ A,   // [M][K] bf16
    const unsigned short* __restrict__ B,   // [N][K] bf16
    const float* __restrict__ bias,         // [N] f32
    float* __restrict__ Cf,                 // f32 out (or null)
    unsigned short* __restrict__ Cb,        // bf16 out (or null)
    int M, int N, int K)
{
    __shared__ char As[128 * 128];
    __shared__ char Bs[128 * 128];

    const int tid  = threadIdx.x;
    const int lane = tid & 63;
    const int w    = tid >> 6;
    const int wm   = w >> 1;
    const int wn   = w & 1;

    // XCD swizzle: consecutive swz ids stay on one XCD -> B-panel L2 reuse
    const int gx  = gridDim.x;
    const int lid = blockIdx.y * gx + blockIdx.x;
    const int nwg = gx * gridDim.y;
    const int cpx = nwg >> 3;                 // nwg % 8 == 0 (768, 256)
    const int swz = (lid & 7) * cpx + (lid >> 3);
    const int m0 = (swz / gx) * 128;
    const int n0 = (swz % gx) * 128;

    f32x4 acc[4][4];
#pragma unroll
    for (int i = 0; i < 4; ++i)
#pragma unroll
        for (int j = 0; j < 4; ++j) acc[i][j] = (f32x4){0.f, 0.f, 0.f, 0.f};

    const int wbase = (tid & ~63);

    for (int k0 = 0; k0 < K; k0 += 64) {
        const char* Ag = (const char*)(A + (size_t)m0 * K + k0);
        const char* Bg = (const char*)(B + (size_t)n0 * K + k0);
#pragma unroll
        for (int i = 0; i < 4; ++i) {
            const int c = i * 256 + tid;
            const int row = c >> 3, cin = c & 7;
            const size_t goff = (size_t)row * (K * 2) + (size_t)((cin ^ (row & 7)) << 4);
            GLOAD_LDS16(Ag + goff, As + (i * 256 + wbase) * 16);
            GLOAD_LDS16(Bg + goff, Bs + (i * 256 + wbase) * 16);
        }
        __syncthreads();

#pragma unroll
        for (int ks = 0; ks < 2; ++ks) {
            const int kch = ks * 4 + (lane >> 4);
            bf16x8 a[4], b[4];
#pragma unroll
            for (int mi = 0; mi < 4; ++mi)
                a[mi] = frag_ld(As, wm * 64 + mi * 16 + (lane & 15), kch);
#pragma unroll
            for (int ni = 0; ni < 4; ++ni)
                b[ni] = frag_ld(Bs, wn * 64 + ni * 16 + (lane & 15), kch);
#pragma unroll
            for (int mi = 0; mi < 4; ++mi)
#pragma unroll
                for (int ni = 0; ni < 4; ++ni)
                    acc[mi][ni] = __builtin_amdgcn_mfma_f32_16x16x32_bf16(
                        a[mi], b[ni], acc[mi][ni], 0, 0, 0);
        }
        __syncthreads();
    }

    const int lc  = lane & 15;
    const int lr4 = (lane >> 4) * 4;
#pragma unroll
    for (int ni = 0; ni < 4; ++ni) {
        const int gcol = n0 + wn * 64 + ni * 16 + lc;
        const float bv = bias[gcol];
#pragma unroll
        for (int mi = 0; mi < 4; ++mi) {
            const int grow0 = m0 + wm * 64 + mi * 16 + lr4;
#pragma unroll
            for (int j = 0; j < 4; ++j) {
                const float v = acc[mi][ni][j] + bv;
                if (Cb) Cb[(size_t)(grow0 + j) * N + gcol] = f2bf(v);
                else    Cf[(size_t)(grow0 + j) * N + gcol] = v;
            }
        }
    }
}

// ---------------- V transpose + PV-slot permutation ----------------
// Vt[bh][d][32 tiles x 64 perm-slots]: within each 64-key tile, position
// p = 32s + 8*l4 + e holds V[t = 32s + 16*(e>>2) + 4*l4 + (e&3)][d] — matches
// the P B-fragment slot map exactly, so flash reads V via plain frag_ld.
__global__ __launch_bounds__(256) void transpose_v(
    const unsigned short* __restrict__ qkvb, unsigned short* __restrict__ Vt)
{
    __shared__ unsigned short vt[64][72];
    const int tid = threadIdx.x;
    const int t0  = blockIdx.x * 64;
    const int bh  = blockIdx.y;
    const int b = bh >> 4, h = bh & 15;
    const unsigned short* src = qkvb + (size_t)(b * GT_SEQ) * (3 * GC) + 2 * GC + h * GDH;
    unsigned short* dstb = Vt + (size_t)bh * GDH * GT_SEQ;

#pragma unroll
    for (int i = 0; i < 2; ++i) {
        const int c = i * 256 + tid;
        const int tr = c >> 3, ch = c & 7;
        *reinterpret_cast<u16x8*>(&vt[tr][ch * 8]) =
            *reinterpret_cast<const u16x8*>(src + (size_t)(t0 + tr) * (3 * GC) + ch * 8);
    }
    __syncthreads();
#pragma unroll
    for (int i = 0; i < 2; ++i) {
        const int c = i * 256 + tid;
        const int d = c >> 3, ch = c & 7;    // ch = chunk: s = ch>>2, l4p = ch&3
        const int s = ch >> 2, l4p = ch & 3;
        u16x8 o;
#pragma unroll
        for (int e = 0; e < 8; ++e) {
            const int tp = s * 32 + (e >> 2) * 16 + l4p * 4 + (e & 3);
            o[e] = vt[tp][d];
        }
        *reinterpret_cast<u16x8*>(dstb + (size_t)d * GT_SEQ + t0 + ch * 8) = o;
    }
}

// ---------------- flash attention v9c: unified K/V frag_ld paths ----------------
// r17 core; V^T LDS read is now plain frag_ld (perm baked into Vt layout) —
// same validated 2-way-free bank pattern as K, half the V address VALU.
__global__ __launch_bounds__(256) void flash_attn_mfma9(
    const unsigned short* __restrict__ qkvb,  // [4096][3072] bf16: q|k|v
    const unsigned short* __restrict__ Vt,    // [32][64][2048] (perm slots)
    unsigned short* __restrict__ O)           // [4096][1024] bf16
{
    __shared__ __align__(16) char Ks[2][64 * 128];   // K tile: row k, 64 d bf16, swizzled
    __shared__ __align__(16) char Vs[2][64 * 128];   // V^T tile: row d, 64 slots, swizzled

    const int tid  = threadIdx.x;
    const int lane = tid & 63;
    const int w    = tid >> 6;               // wave 0..3
    const int l15  = lane & 15;
    const int l4   = lane >> 4;
    const int bid  = blockIdx.x;              // 0..1023
    const int xcd  = bid & 7;
    const int rest = bid >> 3;                // 0..127
    const int bh   = xcd * 4 + (rest & 3);    // 0..31
    const int qb   = 31 - (rest >> 2);        // 0..31 (64-row blocks), heavy first
    const int b    = bh >> 4, h = bh & 15;
    const int q0w  = qb * 64 + w * 16;        // this wave's 16 q rows

    const unsigned short* hQ = qkvb + (size_t)(b * GT_SEQ) * (3 * GC) + h * GDH;
    const char* hKc = (const char*)(qkvb + (size_t)(b * GT_SEQ) * (3 * GC) + GC + h * GDH);
    const char* hVc = (const char*)(Vt + (size_t)bh * GDH * GT_SEQ);

    // all-ones A-fragment: acc_l = mfma(ones, P) -> l_q in every reg
    bf16x8 ones_a;
#pragma unroll
    for (int e = 0; e < 8; ++e) ones_a[e] = (short)0x3F80;

    // Q fragments (scaled in-register once): qf[s], q row = l15, d = s*32+l4*8+e
    bf16x8 qf[2];
#pragma unroll
    for (int s = 0; s < 2; ++s) {
        bf16x8 v = *reinterpret_cast<const bf16x8*>(
            hQ + (size_t)(q0w + l15) * (3 * GC) + s * 32 + l4 * 8);
#pragma unroll
        for (int e = 0; e < 8; ++e)
            v[e] = (short)f2bf(bf2f((unsigned short)v[e]) * QSCALE);
        qf[s] = v;
    }

    f32x4 acc_o[4];
    f32x4 acc_l = (f32x4){0.f, 0.f, 0.f, 0.f};
    float m_r = -1e30f;
#pragma unroll
    for (int nd = 0; nd < 4; ++nd) acc_o[nd] = (f32x4){0.f, 0.f, 0.f, 0.f};

    const int nt = qb + 1;
    const int wbase16 = (tid & ~63) * 16;

    // stage tile t into buffer bb: source pre-swizzled, dest linear (rule 21)
    auto STAGE = [&](int bb, int t) {
        const int k0 = t * 64;
#pragma unroll
        for (int i = 0; i < 2; ++i) {
            const int c = i * 256 + tid;
            const int row = c >> 3, cin = c & 7;
            GLOAD_LDS16(hKc + (size_t)(k0 + row) * (3 * GC * 2) + ((cin ^ (row & 7)) << 4),
                        Ks[bb] + i * 4096 + wbase16);
            GLOAD_LDS16(hVc + (size_t)row * 4096 + (size_t)k0 * 2 + ((cin ^ (row & 7)) << 4),
                        Vs[bb] + i * 4096 + wbase16);
        }
    };

    STAGE(0, 0);
    __syncthreads();

    for (int t = 0; t < nt; ++t) {
        if (t + 1 < nt) STAGE((t + 1) & 1, t + 1);

        const int k0 = t * 64;
        const char* Kb = Ks[t & 1];
        const char* Vb = Vs[t & 1];

        if (k0 <= q0w + 15) {   // wave-uniform skip of fully-masked tiles
            // ---- QK^T swapped: S^T = mfma(K, Q), K fragments from LDS ----
            f32x4 s_acc[4];
#pragma unroll
            for (int ni = 0; ni < 4; ++ni) s_acc[ni] = (f32x4){0.f, 0.f, 0.f, 0.f};
#pragma unroll
            for (int s = 0; s < 2; ++s) {
                bf16x8 kf[4];
#pragma unroll
                for (int ni = 0; ni < 4; ++ni)
                    kf[ni] = frag_ld(Kb, ni * 16 + l15, s * 4 + l4);
#pragma unroll
                for (int ni = 0; ni < 4; ++ni)
                    s_acc[ni] = __builtin_amdgcn_mfma_f32_16x16x32_bf16(
                        kf[ni], qf[s], s_acc[ni], 0, 0, 0);
            }

            // ---- causal mask (partial tiles only): k > q -> -inf ----
            if (k0 + 63 > q0w) {
#pragma unroll
                for (int ni = 0; ni < 4; ++ni)
#pragma unroll
                    for (int j = 0; j < 4; ++j)
                        if (k0 + ni * 16 + l4 * 4 + j > q0w + l15)
                            s_acc[ni][j] = -1e30f;
            }

            // ---- deferred-max: in-lane partial max, rare rescale ----
            float r = fmaxf(fmaxf(s_acc[0][0], s_acc[0][1]),
                            fmaxf(s_acc[0][2], s_acc[0][3]));
#pragma unroll
            for (int ni = 1; ni < 4; ++ni)
                r = fmaxf(r, fmaxf(fmaxf(s_acc[ni][0], s_acc[ni][1]),
                                   fmaxf(s_acc[ni][2], s_acc[ni][3])));
            const int ok = (r <= m_r + 8.f) ? 1 : 0;
            if (!__all(ok)) {
                r = fmaxf(r, __shfl_xor(r, 16));
                r = fmaxf(r, __shfl_xor(r, 32));
                const float mnew = fmaxf(m_r, r);
                const float corr = hw_exp2(m_r - mnew);
                m_r = mnew;
                acc_l *= corr;
#pragma unroll
                for (int nd = 0; nd < 4; ++nd) acc_o[nd] *= corr;
            }

            // ---- exp2 + cvt_pk + PV per s; l via ones-MFMA; V via frag_ld ----
#pragma unroll
            for (int s = 0; s < 2; ++s) {
                union { u32 w4[4]; bf16x8 v; } pw;
                {
                    f32x4 pa, pb;
#pragma unroll
                    for (int j = 0; j < 4; ++j) {
                        pa[j] = hw_exp2(s_acc[2 * s + 0][j] - m_r);
                        pb[j] = hw_exp2(s_acc[2 * s + 1][j] - m_r);
                    }
                    pw.w4[0] = pk_bf16(pa[0], pa[1]);
                    pw.w4[1] = pk_bf16(pa[2], pa[3]);
                    pw.w4[2] = pk_bf16(pb[0], pb[1]);
                    pw.w4[3] = pk_bf16(pb[2], pb[3]);
                }
                acc_l = __builtin_amdgcn_mfma_f32_16x16x32_bf16(
                    ones_a, pw.v, acc_l, 0, 0, 0);
#pragma unroll
                for (int nd = 0; nd < 4; ++nd) {
                    const bf16x8 vf = frag_ld(Vb, nd * 16 + l15, s * 4 + l4);
                    acc_o[nd] = __builtin_amdgcn_mfma_f32_16x16x32_bf16(
                        vf, pw.v, acc_o[nd], 0, 0, 0);
                }
            }
        }

        __syncthreads();
    }

    // ---- epilogue: l = acc_l[0] (same in all regs), normalize, store ----
    {
        const float inv = 1.f / acc_l[0];
        const int q = q0w + l15;
        const size_t rbase = (size_t)(b * GT_SEQ + q) * GC + h * GDH;
#pragma unroll
        for (int nd = 0; nd < 4; ++nd) {
            ushort4 ov;
            ov.x = f2bf(acc_o[nd][0] * inv);
            ov.y = f2bf(acc_o[nd][1] * inv);
            ov.z = f2bf(acc_o[nd][2] * inv);
            ov.w = f2bf(acc_o[nd][3] * inv);
            *reinterpret_cast<ushort4*>(&O[rbase + nd * 16 + l4 * 4]) = ov;
        }
    }
}

extern "C" void kernel_launch(void* const* d_in, const int* in_sizes, int n_in,
                              void* d_out, int out_size, void* d_ws, size_t ws_size,
                              hipStream_t stream) {
    (void)in_sizes; (void)n_in; (void)out_size; (void)ws_size;
    const float* x      = (const float*)d_in[0];
    const float* w_attn = (const float*)d_in[1];
    const float* b_attn = (const float*)d_in[2];
    const float* w_proj = (const float*)d_in[3];
    const float* b_proj = (const float*)d_in[4];
    float* out = (float*)d_out;

    unsigned short* xb   = (unsigned short*)d_ws;            // [4096][1024]
    unsigned short* wab  = xb   + (size_t)GM * GC;           // [3072][1024]
    unsigned short* wpb  = wab  + (size_t)3 * GC * GC;       // [1024][1024]
    unsigned short* qkvb = wpb  + (size_t)GC * GC;           // [4096][3072]
    unsigned short* Vt   = qkvb + (size_t)GM * 3 * GC;       // [32][64][2048]
    unsigned short* aob  = xb;   // reuse: xb dead after GEMM1

    // 0) fused casts: x(4M) | w_attn(3M) | w_proj(1M) = 8M elems
    cast3_f32_bf16<<<dim3(8192), dim3(256), 0, stream>>>(
        x, xb, GM * GC, w_attn, wab, 3 * GC * GC, w_proj, wpb);

    // 1) qkv = x @ w_attn^T + b_attn (bf16), grid 24x32 = 768 (%8==0 for swizzle)
    gemm_mfma_bt<<<dim3(3 * GC / 128, GM / 128), dim3(256), 0, stream>>>(
        xb, wab, b_attn, nullptr, qkvb, GM, 3 * GC, GC);

    // 1.5) V transpose (+ PV-slot permutation) from qkvb -> Vt
    transpose_v<<<dim3(GT_SEQ / 64, GB * GH), dim3(256), 0, stream>>>(qkvb, Vt);

    // 2) flash attention v9c -> aob
    flash_attn_mfma9<<<dim3(1024), dim3(256), 0, stream>>>(qkvb, Vt, aob);

    // 3) out = aob @ w_proj^T + b_proj (f32), grid 8x32 = 256 (%8==0)
    gemm_mfma_bt<<<dim3(GC / 128, GM / 128), dim3(256), 0, stream>>>(
        aob, wpb, b_proj, out, nullptr, GM, GC, GC);
}